// Round 11
// baseline (786.577 us; speedup 1.0000x reference)
//
#include <hip/hip_runtime.h>
#include <hip/hip_bf16.h>

using bf16 = __hip_bfloat16;
typedef __attribute__((ext_vector_type(8))) short short8;   // 8 bf16 = 4 VGPRs
typedef __attribute__((ext_vector_type(4))) float f32x4;    // MFMA C/D frag

#define MFMA_BF16(A,B,C) __builtin_amdgcn_mfma_f32_16x16x32_bf16((A),(B),(C),0,0,0)

static __device__ __forceinline__ unsigned bf16bits(float f) {
  union { bf16 h; unsigned short u; } cv; cv.h = __float2bfloat16(f); return cv.u;
}

// async global->LDS, 16B per lane. LDS dest = wave-uniform base + lane*16.
static __device__ __forceinline__ void gload16(const void* g, void* l) {
  __builtin_amdgcn_global_load_lds(
      (const __attribute__((address_space(1))) void*)g,
      (__attribute__((address_space(3))) void*)l, 16, 0, 0);
}

// ---------------------------------------------------------------------------
// Generic bf16 GEMM: C[M,N] = A[M,K] @ B[N,K]^T (+bias)
// m97 structure: 128x128 tile, BK=32, 4 waves (2x2), 4x4 16x16x32 frags/wave.
// EPI 0: decoder — 1D grid, XCD-chunked bijective swizzle (B-panel L2 reuse);
//        fp32 out via LDS-transpose + dwordx4 stores, synced with
//        __syncthreads (uniform; no asm-ordering subtleties).
// EPI 1: tanh(x*BN_SCALE) -> bf16.  EPI 2: g0p scatter (permuted Wih0).
// ---------------------------------------------------------------------------
template<int EPI>
__global__ __launch_bounds__(256)
void gemm_bt(const bf16* __restrict__ A, const bf16* __restrict__ B,
             const float* __restrict__ bias1, const float* __restrict__ bias2,
             float* __restrict__ Cf, bf16* __restrict__ Cb,
             int M, int N, int K, int Nreal)
{
  __shared__ __align__(1024) bf16 As[128*32];
  __shared__ __align__(1024) bf16 Bs[128*32];
  __shared__ float T[4][16][68];       // EPI0 transpose buffer (wave-private)
  const int tid  = threadIdx.x;
  const int wave = tid >> 6, lane = tid & 63;
  const int wr = wave >> 1, wc = wave & 1;

  int row0, col0;
  if (EPI == 0) {
    // 1D grid, bijective XCD-chunk swizzle (nwg % 8 == 0 by construction:
    // 391*16 = 6256 = 8*782). XCD x owns tiles [x*782, (x+1)*782): panel-major
    // -> the 16 M-tiles of one B-panel run consecutively on one XCD.
    const int nwg  = (N >> 7) * (M >> 7);
    const int q    = nwg >> 3;
    const int tile = (blockIdx.x & 7) * q + (blockIdx.x >> 3);
    const int mt   = M >> 7;
    col0 = (tile / mt) * 128;
    row0 = (tile % mt) * 128;
  } else {
    row0 = blockIdx.y * 128;
    col0 = blockIdx.x * 128;
  }

  f32x4 acc[4][4];
  #pragma unroll
  for (int m = 0; m < 4; ++m)
    #pragma unroll
    for (int n = 0; n < 4; ++n) { f32x4 z = {0.f,0.f,0.f,0.f}; acc[m][n] = z; }

  const int r_sub = lane >> 2;   // 0..15 (row within 16-row stage group)
  const int kc    = lane & 3;    // 16B chunk within 64B row

  for (int k0 = 0; k0 < K; k0 += 32) {
    __syncthreads();
    #pragma unroll
    for (int j = 0; j < 2; ++j) {
      const int rb = wave*32 + j*16;
      gload16(A + (size_t)(row0 + rb + r_sub)*K + k0 + kc*8,
              (void*)((char*)As + (size_t)rb*64));
      gload16(B + (size_t)(col0 + rb + r_sub)*K + k0 + kc*8,
              (void*)((char*)Bs + (size_t)rb*64));
    }
    __syncthreads();

    short8 af[4], bfv[4];
    #pragma unroll
    for (int m = 0; m < 4; ++m)
      af[m] = *(const short8*)(As + (wr*64 + m*16 + (lane&15))*32 + (lane>>4)*8);
    #pragma unroll
    for (int n = 0; n < 4; ++n)
      bfv[n] = *(const short8*)(Bs + (wc*64 + n*16 + (lane&15))*32 + (lane>>4)*8);
    #pragma unroll
    for (int m = 0; m < 4; ++m)
      #pragma unroll
      for (int n = 0; n < 4; ++n)
        acc[m][n] = MFMA_BF16(af[m], bfv[n], acc[m][n]);
  }

  const float BN_SCALE = 0.9999950000374997f;  // 1/sqrt(1+1e-5)

  if (EPI == 0) {
    // LDS-transpose epilogue, __syncthreads-synced, coalesced dwordx4 stores.
    const int rr  = lane >> 2;           // read row 0..15
    const int cc  = (lane & 3) * 16;     // 16-float chunk start
    const bool colsafe = (col0 + wc*64 + 63 < Nreal);
    #pragma unroll
    for (int m = 0; m < 4; ++m) {
      __syncthreads();                   // previous m's reads complete
      #pragma unroll
      for (int n = 0; n < 4; ++n) {
        const int cg = col0 + wc*64 + n*16 + (lane&15);
        const float bb = bias1 ? bias1[cg < Nreal ? cg : 0] : 0.f;
        #pragma unroll
        for (int j = 0; j < 4; ++j)
          T[wave][(lane>>4)*4 + j][n*16 + (lane&15)] = acc[m][n][j] + bb;
      }
      __syncthreads();                   // T writes visible
      const int grow = row0 + wr*64 + m*16 + rr;
      float* dst = Cf + (size_t)grow*Nreal + col0 + wc*64 + cc;
      if (colsafe) {
        #pragma unroll
        for (int k = 0; k < 4; ++k)
          *(float4*)(dst + k*4) = *(const float4*)&T[wave][rr][cc + k*4];
      } else {
        #pragma unroll
        for (int k = 0; k < 16; ++k) {
          const int cg = col0 + wc*64 + cc + k;
          if (cg < Nreal) dst[k] = T[wave][rr][cc + k];
        }
      }
    }
  } else {
    #pragma unroll
    for (int m = 0; m < 4; ++m) {
      const int rg0 = row0 + wr*64 + m*16 + ((lane>>4)<<2);
      #pragma unroll
      for (int n = 0; n < 4; ++n) {
        const int cg = col0 + wc*64 + n*16 + (lane&15);
        if (EPI == 2) {
          const int bq = cg >> 4, q = cg & 15;
          const int orig = (q>>2)*1024 + bq*4 + (q&3);   // permuted -> original col
          const float bb = bias1[orig] + bias2[orig];
          #pragma unroll
          for (int j = 0; j < 4; ++j) {
            const int row = rg0 + j;
            Cf[((size_t)bq*64 + (row>>5))*512 + (size_t)(row&31)*16 + q]
                = acc[m][n][j] + bb;
          }
        } else if (cg < Nreal) {
          float bb = 0.f;
          if (bias1) bb += bias1[cg];
          if (bias2) bb += bias2[cg];
          #pragma unroll
          for (int j = 0; j < 4; ++j) {
            float v = acc[m][n][j] + bb;
            v = tanhf(v * BN_SCALE);
            Cb[(size_t)(rg0+j)*Nreal + cg] = __float2bfloat16(v);
          }
        }
      }
    }
  }
}

// ---------------------------------------------------------------------------
// Persistent LSTM recurrence — BYTE-IDENTICAL to round 9 (proven 377 µs).
// Weights: LDS (96KB, staged once). h reads: normal cached loads (per-XCD L2
// as broadcast cache). h publish: 8B agent-scope relaxed stores (LLC).
// Flag publish/poll: inline-asm sc0 sc1 relaxed ops (no buffer_wbl2 — the
// release's full-L2 writeback was the per-step cost of rounds 4-7; asm
// volatile prevents the compiler reordering that hung round 8).
// ---------------------------------------------------------------------------
__global__ __launch_bounds__(256, 1)
void k_lstm_persist(const bf16* __restrict__ hinit, const float* __restrict__ cx,
                    const bf16* __restrict__ Wpack, const float* __restrict__ g0p,
                    const float* __restrict__ bih1, const float* __restrict__ bhh1,
                    bf16* __restrict__ h0_all, bf16* __restrict__ h1_all,
                    float* __restrict__ tail, unsigned* __restrict__ flags)
{
  const int b    = blockIdx.x;
  const int tid  = threadIdx.x;
  const int wave = tid >> 6, lane = tid & 63;

  __shared__ __align__(1024) bf16 Wlds[96*512];   // 96 KB: [chunk][lane][8]
  __shared__ float P[4][2][32][20];               // partial sums (padded)

  // one-time: stage this block's packed weights into LDS
  const bf16* wbase = Wpack + (size_t)b * 96 * 512;
  #pragma unroll
  for (int it = 0; it < 24; ++it) {
    const int chunk = it*4 + wave;                // wave-uniform
    gload16(wbase + (size_t)chunk*512 + lane*8,
            (void*)((char*)Wlds + (size_t)chunk*1024));
  }

  // gate/cell phase mapping: one LSTM cell per thread
  const int layer = tid >> 7;
  const int cell  = tid & 127;
  const int r     = cell >> 2;
  const int hc    = cell & 3;
  const int col   = b*4 + hc;
  float creg = cx[(size_t)layer*32768 + (size_t)r*1024 + col];
  float bsum[4];
  #pragma unroll
  for (int g = 0; g < 4; ++g)
    bsum[g] = (layer == 1) ? (bih1[g*1024 + col] + bhh1[g*1024 + col]) : 0.f;

  const int arow = lane & 15;
  const int koff = (lane >> 4) * 8;

  // per-lane poll pointers (wave 0 only uses them)
  const unsigned* fp0 = flags + (lane*4+0)*32;
  const unsigned* fp1 = flags + (lane*4+1)*32;
  const unsigned* fp2 = flags + (lane*4+2)*32;
  const unsigned* fp3 = flags + (lane*4+3)*32;

  __syncthreads();   // weights staged (drains vmcnt incl. global_load_lds)

  for (int s = 0; s < 65; ++s) {
    const bf16* hA = (s == 0) ? hinit           : h0_all + (size_t)(s-1)*32768;
    const bf16* hB = (s <= 1) ? (hinit + 32768) : h1_all + (size_t)(s-2)*32768;

    // normal cached h loads (L2 broadcast); all issued up front
    short8 a0[8], a1[8], c0[8], c1[8];
    #pragma unroll
    for (int i = 0; i < 8; ++i) {
      const int kb = wave*256 + i*32 + koff;
      a0[i] = *(const short8*)(hA + (size_t)arow*1024      + kb);
      a1[i] = *(const short8*)(hA + (size_t)(arow+16)*1024 + kb);
      c0[i] = *(const short8*)(hB + (size_t)arow*1024      + kb);
      c1[i] = *(const short8*)(hB + (size_t)(arow+16)*1024 + kb);
    }
    float gpre[4] = {0.f, 0.f, 0.f, 0.f};
    if (layer == 0 && s < 64) {
      const float* gr = g0p + ((size_t)(b*64 + s)*32 + r)*16;
      #pragma unroll
      for (int g = 0; g < 4; ++g) gpre[g] = gr[g*4 + hc];
    }

    f32x4 z = {0.f,0.f,0.f,0.f};
    f32x4 acc00 = z, acc01 = z, acc10 = z, acc11 = z;
    #pragma unroll
    for (int i = 0; i < 8; ++i) {
      const int ks = wave*8 + i;
      short8 w0 = *(const short8*)(Wlds + ((size_t)(     ks)*64 + lane)*8);
      short8 w1 = *(const short8*)(Wlds + ((size_t)(32 + ks)*64 + lane)*8);
      short8 w2 = *(const short8*)(Wlds + ((size_t)(64 + ks)*64 + lane)*8);
      acc00 = MFMA_BF16(a0[i], w0, acc00);   // layer0: Whh0 @ h0[s-1]
      acc01 = MFMA_BF16(a1[i], w0, acc01);
      acc10 = MFMA_BF16(a0[i], w1, acc10);   // layer1: Wih1 @ h0[s-1]
      acc11 = MFMA_BF16(a1[i], w1, acc11);
      acc10 = MFMA_BF16(c0[i], w2, acc10);   // layer1 += Whh1 @ h1[s-2]
      acc11 = MFMA_BF16(c1[i], w2, acc11);
    }

    #pragma unroll
    for (int j = 0; j < 4; ++j) {
      const int pr = (lane >> 4)*4 + j;
      P[wave][0][pr     ][lane & 15] = acc00[j];
      P[wave][0][pr + 16][lane & 15] = acc01[j];
      P[wave][1][pr     ][lane & 15] = acc10[j];
      P[wave][1][pr + 16][lane & 15] = acc11[j];
    }
    __syncthreads();                         // #1: P complete

    const int t = s - layer;
    if (t >= 0 && t < 64) {
      float v[4];
      #pragma unroll
      for (int g = 0; g < 4; ++g) {
        const int j = g*4 + hc;
        v[g] = P[0][layer][r][j] + P[1][layer][r][j]
             + P[2][layer][r][j] + P[3][layer][r][j] + bsum[g] + gpre[g];
      }
      const float iv = 1.f/(1.f + expf(-v[0]));
      const float fv = 1.f/(1.f + expf(-v[1]));
      const float gv = tanhf(v[2]);
      const float ov = 1.f/(1.f + expf(-v[3]));
      creg = fv*creg + iv*gv;
      const float hn = ov*tanhf(creg);
      // gather 4 cells -> one 8B agent-relaxed store straight to LLC
      unsigned hu  = bf16bits(hn);
      unsigned p01 = hu | ((unsigned)__shfl_xor((int)hu, 1) << 16);
      unsigned p23 = (unsigned)__shfl_xor((int)p01, 2);
      if (hc == 0) {
        bf16* hp = (layer ? h1_all : h0_all) + (size_t)t*32768 + (size_t)r*1024 + b*4;
        unsigned long long v64 = (unsigned long long)p01
                               | ((unsigned long long)p23 << 32);
        __hip_atomic_store((unsigned long long*)hp, v64,
                           __ATOMIC_RELAXED, __HIP_MEMORY_SCOPE_AGENT);
      }
      if (t == 63) {
        tail[(size_t)layer*32768 + (size_t)r*1024 + col]         = hn;
        tail[65536 + (size_t)layer*32768 + (size_t)r*1024 + col] = creg;
      }
    }
    if (s == 64) break;

    __syncthreads();                         // #2: drain h publishes (vmcnt 0)
    if (tid == 0) {
      // RELAXED publish straight to LLC (sc1), pinned by asm volatile:
      // no buffer_wbl2, no compiler reordering.
      asm volatile("global_store_dword %0, %1, off sc0 sc1\n\t"
                   "s_waitcnt vmcnt(0)"
                   :: "v"(flags + b*32), "v"((unsigned)(s + 1)) : "memory");
    }
    if (wave == 0) {                         // only wave 0 polls
      const unsigned su = (unsigned)s;
      for (;;) {
        unsigned v0, v1, v2, v3;
        asm volatile("global_load_dword %0, %1, off sc0 sc1" : "=v"(v0) : "v"(fp0));
        asm volatile("global_load_dword %0, %1, off sc0 sc1" : "=v"(v1) : "v"(fp1));
        asm volatile("global_load_dword %0, %1, off sc0 sc1" : "=v"(v2) : "v"(fp2));
        asm volatile("global_load_dword %0, %1, off sc0 sc1" : "=v"(v3) : "v"(fp3));
        asm volatile("s_waitcnt vmcnt(0)" ::: "memory");
        bool ok = (v0 > su) & (v1 > su) & (v2 > su) & (v3 > su);
        if (__all(ok)) break;
        __builtin_amdgcn_s_sleep(1);
      }
    }
    __syncthreads();                         // #3: release all waves
    asm volatile("" ::: "memory");           // no hoisting of h loads above
    __builtin_amdgcn_sched_barrier(0);
  }
}

// ---------------------------------------------------------------------------
// Pack Whh0 / Wih1 / Whh1 into per-block MFMA-fragment order (bf16).
// ---------------------------------------------------------------------------
__global__ __launch_bounds__(256)
void k_pack(const float* __restrict__ Whh0, const float* __restrict__ Wih1,
            const float* __restrict__ Whh1, bf16* __restrict__ Wpack)
{
  const int b = blockIdx.x;
  #pragma unroll 4
  for (int it = 0; it < 24; ++it) {
    const int idx = it*256 + threadIdx.x;
    const int chunkp = idx >> 6;            // 0..95
    const int l = idx & 63;
    const int p = chunkp >> 5, c = chunkp & 31;
    const float* W = (p == 0) ? Whh0 : (p == 1 ? Wih1 : Whh1);
    const int j = l & 15;
    const int row = (j>>2)*1024 + b*4 + (j&3);
    const int k = c*32 + (l>>4)*8;
    const float* src = W + (size_t)row*1024 + k;
    bf16* dst = Wpack + ((size_t)(b*96 + chunkp)*64 + l)*8;
    #pragma unroll
    for (int q = 0; q < 8; ++q) dst[q] = __float2bfloat16(src[q]);
  }
}

// ---------------------------------------------------------------------------
// small helpers
// ---------------------------------------------------------------------------
__global__ void k_cvt(const float* __restrict__ s, bf16* __restrict__ d, long n) {
  long i = (long)blockIdx.x*blockDim.x + threadIdx.x;
  if (i < n) d[i] = __float2bfloat16(s[i]);
}

// Wih0 cast with ROW PERMUTATION: dst row n <- src row ((n>>2)&3)*1024 + (n>>4)*4 + (n&3)
__global__ void k_cvt_perm(const float* __restrict__ src, bf16* __restrict__ dst) {
  const int n = blockIdx.x;                 // 0..4095 (permuted row)
  const int orig = ((n>>2)&3)*1024 + (n>>4)*4 + (n&3);
  const float4 v = ((const float4*)(src + (size_t)orig*512))[threadIdx.x];
  bf16* d = dst + (size_t)n*512 + threadIdx.x*4;
  d[0] = __float2bfloat16(v.x); d[1] = __float2bfloat16(v.y);
  d[2] = __float2bfloat16(v.z); d[3] = __float2bfloat16(v.w);
}

__global__ void k_cvt_pad(const float* __restrict__ s, bf16* __restrict__ d,
                          long n, long nrows_real, int rowlen) {
  long i = (long)blockIdx.x*blockDim.x + threadIdx.x;
  if (i < n) {
    long r = i / rowlen;
    d[i] = (r < nrows_real) ? __float2bfloat16(s[i]) : __float2bfloat16(0.f);
  }
}

__global__ void k_init(const float* __restrict__ hx, bf16* __restrict__ hinit,
                       unsigned* __restrict__ flags) {
  int i = blockIdx.x*blockDim.x + threadIdx.x;
  if (i < 8192) flags[i] = 0u;
  if (i < 65536) hinit[i] = __float2bfloat16(hx[i]);
}

__global__ void k_embed(const int* __restrict__ ids, const float* __restrict__ emb_w,
                        bf16* __restrict__ out) {
  const int row = blockIdx.x;
  const int tok = ids[row];
  const float4 v = ((const float4*)(emb_w + (size_t)tok*512))[threadIdx.x];
  bf16* d = out + (size_t)row*512 + threadIdx.x*4;
  d[0] = __float2bfloat16(v.x); d[1] = __float2bfloat16(v.y);
  d[2] = __float2bfloat16(v.z); d[3] = __float2bfloat16(v.w);
}

// ---------------------------------------------------------------------------
extern "C" void kernel_launch(void* const* d_in, const int* in_sizes, int n_in,
                              void* d_out, int out_size, void* d_ws, size_t ws_size,
                              hipStream_t stream) {
  const int*   ids  = (const int*)d_in[0];
  const float* hx   = (const float*)d_in[1];
  const float* cx   = (const float*)d_in[2];
  const float* embw = (const float*)d_in[3];
  const float* Wih0 = (const float*)d_in[4];
  const float* Whh0 = (const float*)d_in[5];
  const float* bih0 = (const float*)d_in[6];
  const float* bhh0 = (const float*)d_in[7];
  const float* Wih1 = (const float*)d_in[8];
  const float* Whh1 = (const float*)d_in[9];
  const float* bih1 = (const float*)d_in[10];
  const float* bhh1 = (const float*)d_in[11];
  const float* Wp   = (const float*)d_in[12];
  const float* bp   = (const float*)d_in[13];
  const float* Wd   = (const float*)d_in[14];
  const float* bd   = (const float*)d_in[15];
  float* out = (float*)d_out;

  char* w = (char*)d_ws;
  bf16* Wih0b = (bf16*)w; w += 4096l*512*2;       // permuted rows
  bf16* Wpack = (bf16*)w; w += 256l*96*64*8*2;    // 24 MB packed recurrent weights
  bf16* Wpb   = (bf16*)w; w += 512l*1024*2;
  bf16* Wdb   = (bf16*)w; w += 50048l*512*2;
  bf16* embb  = (bf16*)w; w += 2048l*512*2;
  float* g0p  = (float*)w; w += 2048l*4096*4;     // [b][t][r][q] layout
  bf16* h0a   = (bf16*)w; w += 2048l*1024*2;
  bf16* h1a   = (bf16*)w; w += 2048l*1024*2;
  bf16* hinit = (bf16*)w; w += 2l*32*1024*2;
  bf16* pb    = (bf16*)w; w += 2048l*512*2;
  unsigned* flags = (unsigned*)w; w += 8192*4;

  k_cvt_perm<<<4096, 128, 0, stream>>>(Wih0, Wih0b);
  k_cvt<<<(512l*1024 + 255)/256, 256, 0, stream>>>(Wp, Wpb, 512l*1024);
  k_cvt_pad<<<(50048l*512 + 255)/256, 256, 0, stream>>>(Wd, Wdb, 50048l*512, 50000, 512);
  k_init<<<256, 256, 0, stream>>>(hx, hinit, flags);
  k_embed<<<2048, 128, 0, stream>>>(ids, embw, embb);
  k_pack<<<256, 256, 0, stream>>>(Whh0, Wih1, Whh1, Wpack);

  // layer-0 input-side GEMM for ALL timesteps -> g0p layout; folds bih0+bhh0
  gemm_bt<2><<<dim3(32, 16), 256, 0, stream>>>(
      embb, Wih0b, bih0, bhh0, g0p, nullptr, 2048, 4096, 512, 4096);

  // persistent pipelined recurrence: one dispatch, 65 super-steps
  float* tail = out + 102400000l;
  k_lstm_persist<<<256, 256, 0, stream>>>(hinit, cx, Wpack, g0p, bih1, bhh1,
                                          h0a, h1a, tail, flags);

  // predictor: Linear + BN(eval) + tanh -> bf16
  gemm_bt<1><<<dim3(4, 16), 256, 0, stream>>>(
      h1a, Wpb, bp, nullptr, nullptr, pb, 2048, 512, 1024, 512);

  // decoder: [2048,512] @ [50048,512]^T (padded), 1D swizzled grid,
  // coalesced fp32 epilogue, guarded store to 50000
  gemm_bt<0><<<391*16, 256, 0, stream>>>(
      pb, Wdb, bd, nullptr, out, nullptr, 2048, 50048, 512, 50000);
}

// Round 13
// 773.150 us; speedup vs baseline: 1.0174x; 1.0174x over previous
//
#include <hip/hip_runtime.h>
#include <hip/hip_bf16.h>

using bf16 = __hip_bfloat16;
typedef __attribute__((ext_vector_type(8))) short short8;   // 8 bf16 = 4 VGPRs
typedef __attribute__((ext_vector_type(4))) float f32x4;    // MFMA C/D frag

#define MFMA_BF16(A,B,C) __builtin_amdgcn_mfma_f32_16x16x32_bf16((A),(B),(C),0,0,0)

static __device__ __forceinline__ unsigned bf16bits(float f) {
  union { bf16 h; unsigned short u; } cv; cv.h = __float2bfloat16(f); return cv.u;
}

// async global->LDS, 16B per lane. LDS dest = wave-uniform base + lane*16.
static __device__ __forceinline__ void gload16(const void* g, void* l) {
  __builtin_amdgcn_global_load_lds(
      (const __attribute__((address_space(1))) void*)g,
      (__attribute__((address_space(3))) void*)l, 16, 0, 0);
}

// ---------------------------------------------------------------------------
// Generic bf16 GEMM: C[M,N] = A[M,K] @ B[N,K]^T (+bias)
// m97 structure: 128x128 tile, BK=32, 4 waves (2x2), 4x4 16x16x32 frags/wave.
// EPI 0: decoder — 1D grid with bijective XCD-chunk swizzle, fp32 out,
//        round-9 scalar-store epilogue (proven).
// EPI 1: tanh(x*BN_SCALE) -> bf16.  EPI 2: g0p scatter (permuted Wih0).
// ---------------------------------------------------------------------------
template<int EPI>
__global__ __launch_bounds__(256)
void gemm_bt(const bf16* __restrict__ A, const bf16* __restrict__ B,
             const float* __restrict__ bias1, const float* __restrict__ bias2,
             float* __restrict__ Cf, bf16* __restrict__ Cb,
             int M, int N, int K, int Nreal)
{
  __shared__ __align__(1024) bf16 As[128*32];
  __shared__ __align__(1024) bf16 Bs[128*32];
  const int tid  = threadIdx.x;
  const int wave = tid >> 6, lane = tid & 63;
  const int wr = wave >> 1, wc = wave & 1;

  int row0, col0;
  if (EPI == 0) {
    // 1D grid, bijective XCD-chunk swizzle (nwg = 391*16 = 6256 = 8*782).
    // XCD x owns a contiguous panel-major tile range -> B-panel L2 reuse.
    const int nwg  = (N >> 7) * (M >> 7);
    const int q    = nwg >> 3;
    const int tile = (blockIdx.x & 7) * q + (blockIdx.x >> 3);
    const int mt   = M >> 7;
    col0 = (tile / mt) * 128;
    row0 = (tile % mt) * 128;
  } else {
    row0 = blockIdx.y * 128;
    col0 = blockIdx.x * 128;
  }

  f32x4 acc[4][4];
  #pragma unroll
  for (int m = 0; m < 4; ++m)
    #pragma unroll
    for (int n = 0; n < 4; ++n) { f32x4 z = {0.f,0.f,0.f,0.f}; acc[m][n] = z; }

  const int r_sub = lane >> 2;   // 0..15 (row within 16-row stage group)
  const int kc    = lane & 3;    // 16B chunk within 64B row

  for (int k0 = 0; k0 < K; k0 += 32) {
    __syncthreads();
    #pragma unroll
    for (int j = 0; j < 2; ++j) {
      const int rb = wave*32 + j*16;
      gload16(A + (size_t)(row0 + rb + r_sub)*K + k0 + kc*8,
              (void*)((char*)As + (size_t)rb*64));
      gload16(B + (size_t)(col0 + rb + r_sub)*K + k0 + kc*8,
              (void*)((char*)Bs + (size_t)rb*64));
    }
    __syncthreads();

    short8 af[4], bfv[4];
    #pragma unroll
    for (int m = 0; m < 4; ++m)
      af[m] = *(const short8*)(As + (wr*64 + m*16 + (lane&15))*32 + (lane>>4)*8);
    #pragma unroll
    for (int n = 0; n < 4; ++n)
      bfv[n] = *(const short8*)(Bs + (wc*64 + n*16 + (lane&15))*32 + (lane>>4)*8);
    #pragma unroll
    for (int m = 0; m < 4; ++m)
      #pragma unroll
      for (int n = 0; n < 4; ++n)
        acc[m][n] = MFMA_BF16(af[m], bfv[n], acc[m][n]);
  }

  const float BN_SCALE = 0.9999950000374997f;  // 1/sqrt(1+1e-5)
  #pragma unroll
  for (int m = 0; m < 4; ++m) {
    const int rg0 = row0 + wr*64 + m*16 + ((lane>>4)<<2);
    #pragma unroll
    for (int n = 0; n < 4; ++n) {
      const int cg = col0 + wc*64 + n*16 + (lane&15);
      if (EPI == 2) {
        const int bq = cg >> 4, q = cg & 15;
        const int orig = (q>>2)*1024 + bq*4 + (q&3);   // permuted -> original col
        const float bb = bias1[orig] + bias2[orig];
        #pragma unroll
        for (int j = 0; j < 4; ++j) {
          const int row = rg0 + j;
          Cf[((size_t)bq*64 + (row>>5))*512 + (size_t)(row&31)*16 + q]
              = acc[m][n][j] + bb;
        }
      } else if (cg < Nreal) {
        float bb = 0.f;
        if (bias1) bb += bias1[cg];
        if (bias2) bb += bias2[cg];
        #pragma unroll
        for (int j = 0; j < 4; ++j) {
          float v = acc[m][n][j] + bb;
          if (EPI == 1) {
            v = tanhf(v * BN_SCALE);
            Cb[(size_t)(rg0+j)*Nreal + cg] = __float2bfloat16(v);
          } else {
            Cf[(size_t)(rg0+j)*Nreal + cg] = v;
          }
        }
      }
    }
  }
}

// ---------------------------------------------------------------------------
// Persistent LSTM recurrence — EXACT round-9/11 proven structure (incl.
// s_sleep(1) poll). Weights: LDS (96KB, staged once). h reads: normal cached
// loads (per-XCD L2 as broadcast cache). h publish: 8B agent-relaxed stores
// (LLC). Flag publish/poll: inline-asm sc0 sc1 relaxed ops (no buffer_wbl2;
// asm volatile prevents the compiler reordering that hung round 8).
// ---------------------------------------------------------------------------
__global__ __launch_bounds__(256, 1)
void k_lstm_persist(const bf16* __restrict__ hinit, const float* __restrict__ cx,
                    const bf16* __restrict__ Wpack, const float* __restrict__ g0p,
                    const float* __restrict__ bih1, const float* __restrict__ bhh1,
                    bf16* __restrict__ h0_all, bf16* __restrict__ h1_all,
                    float* __restrict__ tail, unsigned* __restrict__ flags)
{
  const int b    = blockIdx.x;
  const int tid  = threadIdx.x;
  const int wave = tid >> 6, lane = tid & 63;

  __shared__ __align__(1024) bf16 Wlds[96*512];   // 96 KB: [chunk][lane][8]
  __shared__ float P[4][2][32][20];               // partial sums (padded)

  // one-time: stage this block's packed weights into LDS
  const bf16* wbase = Wpack + (size_t)b * 96 * 512;
  #pragma unroll
  for (int it = 0; it < 24; ++it) {
    const int chunk = it*4 + wave;                // wave-uniform
    gload16(wbase + (size_t)chunk*512 + lane*8,
            (void*)((char*)Wlds + (size_t)chunk*1024));
  }

  // gate/cell phase mapping: one LSTM cell per thread
  const int layer = tid >> 7;
  const int cell  = tid & 127;
  const int r     = cell >> 2;
  const int hc    = cell & 3;
  const int col   = b*4 + hc;
  float creg = cx[(size_t)layer*32768 + (size_t)r*1024 + col];
  float bsum[4];
  #pragma unroll
  for (int g = 0; g < 4; ++g)
    bsum[g] = (layer == 1) ? (bih1[g*1024 + col] + bhh1[g*1024 + col]) : 0.f;

  const int arow = lane & 15;
  const int koff = (lane >> 4) * 8;

  // per-lane poll pointers (wave 0 only uses them)
  const unsigned* fp0 = flags + (lane*4+0)*32;
  const unsigned* fp1 = flags + (lane*4+1)*32;
  const unsigned* fp2 = flags + (lane*4+2)*32;
  const unsigned* fp3 = flags + (lane*4+3)*32;

  __syncthreads();   // weights staged (drains vmcnt incl. global_load_lds)

  for (int s = 0; s < 65; ++s) {
    const bf16* hA = (s == 0) ? hinit           : h0_all + (size_t)(s-1)*32768;
    const bf16* hB = (s <= 1) ? (hinit + 32768) : h1_all + (size_t)(s-2)*32768;

    // normal cached h loads (L2 broadcast); all issued up front
    short8 a0[8], a1[8], c0[8], c1[8];
    #pragma unroll
    for (int i = 0; i < 8; ++i) {
      const int kb = wave*256 + i*32 + koff;
      a0[i] = *(const short8*)(hA + (size_t)arow*1024      + kb);
      a1[i] = *(const short8*)(hA + (size_t)(arow+16)*1024 + kb);
      c0[i] = *(const short8*)(hB + (size_t)arow*1024      + kb);
      c1[i] = *(const short8*)(hB + (size_t)(arow+16)*1024 + kb);
    }
    float gpre[4] = {0.f, 0.f, 0.f, 0.f};
    if (layer == 0 && s < 64) {
      const float* gr = g0p + ((size_t)(b*64 + s)*32 + r)*16;
      #pragma unroll
      for (int g = 0; g < 4; ++g) gpre[g] = gr[g*4 + hc];
    }

    f32x4 z = {0.f,0.f,0.f,0.f};
    f32x4 acc00 = z, acc01 = z, acc10 = z, acc11 = z;
    #pragma unroll
    for (int i = 0; i < 8; ++i) {
      const int ks = wave*8 + i;
      short8 w0 = *(const short8*)(Wlds + ((size_t)(     ks)*64 + lane)*8);
      short8 w1 = *(const short8*)(Wlds + ((size_t)(32 + ks)*64 + lane)*8);
      short8 w2 = *(const short8*)(Wlds + ((size_t)(64 + ks)*64 + lane)*8);
      acc00 = MFMA_BF16(a0[i], w0, acc00);   // layer0: Whh0 @ h0[s-1]
      acc01 = MFMA_BF16(a1[i], w0, acc01);
      acc10 = MFMA_BF16(a0[i], w1, acc10);   // layer1: Wih1 @ h0[s-1]
      acc11 = MFMA_BF16(a1[i], w1, acc11);
      acc10 = MFMA_BF16(c0[i], w2, acc10);   // layer1 += Whh1 @ h1[s-2]
      acc11 = MFMA_BF16(c1[i], w2, acc11);
    }

    #pragma unroll
    for (int j = 0; j < 4; ++j) {
      const int pr = (lane >> 4)*4 + j;
      P[wave][0][pr     ][lane & 15] = acc00[j];
      P[wave][0][pr + 16][lane & 15] = acc01[j];
      P[wave][1][pr     ][lane & 15] = acc10[j];
      P[wave][1][pr + 16][lane & 15] = acc11[j];
    }
    __syncthreads();                         // #1: P complete

    const int t = s - layer;
    if (t >= 0 && t < 64) {
      float v[4];
      #pragma unroll
      for (int g = 0; g < 4; ++g) {
        const int j = g*4 + hc;
        v[g] = P[0][layer][r][j] + P[1][layer][r][j]
             + P[2][layer][r][j] + P[3][layer][r][j] + bsum[g] + gpre[g];
      }
      const float iv = 1.f/(1.f + expf(-v[0]));
      const float fv = 1.f/(1.f + expf(-v[1]));
      const float gv = tanhf(v[2]);
      const float ov = 1.f/(1.f + expf(-v[3]));
      creg = fv*creg + iv*gv;
      const float hn = ov*tanhf(creg);
      // gather 4 cells -> one 8B agent-relaxed store straight to LLC
      unsigned hu  = bf16bits(hn);
      unsigned p01 = hu | ((unsigned)__shfl_xor((int)hu, 1) << 16);
      unsigned p23 = (unsigned)__shfl_xor((int)p01, 2);
      if (hc == 0) {
        bf16* hp = (layer ? h1_all : h0_all) + (size_t)t*32768 + (size_t)r*1024 + b*4;
        unsigned long long v64 = (unsigned long long)p01
                               | ((unsigned long long)p23 << 32);
        __hip_atomic_store((unsigned long long*)hp, v64,
                           __ATOMIC_RELAXED, __HIP_MEMORY_SCOPE_AGENT);
      }
      if (t == 63) {
        tail[(size_t)layer*32768 + (size_t)r*1024 + col]         = hn;
        tail[65536 + (size_t)layer*32768 + (size_t)r*1024 + col] = creg;
      }
    }
    if (s == 64) break;

    __syncthreads();                         // #2: drain h publishes (vmcnt 0)
    if (tid == 0) {
      // RELAXED publish straight to LLC (sc1), pinned by asm volatile:
      // no buffer_wbl2, no compiler reordering.
      asm volatile("global_store_dword %0, %1, off sc0 sc1\n\t"
                   "s_waitcnt vmcnt(0)"
                   :: "v"(flags + b*32), "v"((unsigned)(s + 1)) : "memory");
    }
    if (wave == 0) {                         // only wave 0 polls
      const unsigned su = (unsigned)s;
      for (;;) {
        unsigned v0, v1, v2, v3;
        asm volatile("global_load_dword %0, %1, off sc0 sc1" : "=v"(v0) : "v"(fp0));
        asm volatile("global_load_dword %0, %1, off sc0 sc1" : "=v"(v1) : "v"(fp1));
        asm volatile("global_load_dword %0, %1, off sc0 sc1" : "=v"(v2) : "v"(fp2));
        asm volatile("global_load_dword %0, %1, off sc0 sc1" : "=v"(v3) : "v"(fp3));
        asm volatile("s_waitcnt vmcnt(0)" ::: "memory");
        bool ok = (v0 > su) & (v1 > su) & (v2 > su) & (v3 > su);
        if (__all(ok)) break;
        __builtin_amdgcn_s_sleep(1);
      }
    }
    __syncthreads();                         // #3: release all waves
    asm volatile("" ::: "memory");           // no hoisting of h loads above
    __builtin_amdgcn_sched_barrier(0);
  }
}

// ---------------------------------------------------------------------------
// Pack Whh0 / Wih1 / Whh1 into per-block MFMA-fragment order (bf16).
// ---------------------------------------------------------------------------
__global__ __launch_bounds__(256)
void k_pack(const float* __restrict__ Whh0, const float* __restrict__ Wih1,
            const float* __restrict__ Whh1, bf16* __restrict__ Wpack)
{
  const int b = blockIdx.x;
  #pragma unroll 4
  for (int it = 0; it < 24; ++it) {
    const int idx = it*256 + threadIdx.x;
    const int chunkp = idx >> 6;            // 0..95
    const int l = idx & 63;
    const int p = chunkp >> 5, c = chunkp & 31;
    const float* W = (p == 0) ? Whh0 : (p == 1 ? Wih1 : Whh1);
    const int j = l & 15;
    const int row = (j>>2)*1024 + b*4 + (j&3);
    const int k = c*32 + (l>>4)*8;
    const float* src = W + (size_t)row*1024 + k;
    bf16* dst = Wpack + ((size_t)(b*96 + chunkp)*64 + l)*8;
    #pragma unroll
    for (int q = 0; q < 8; ++q) dst[q] = __float2bfloat16(src[q]);
  }
}

// ---------------------------------------------------------------------------
// small helpers
// ---------------------------------------------------------------------------
__global__ void k_cvt(const float* __restrict__ s, bf16* __restrict__ d, long n) {
  long i = (long)blockIdx.x*blockDim.x + threadIdx.x;
  if (i < n) d[i] = __float2bfloat16(s[i]);
}

// Wih0 cast with ROW PERMUTATION: dst row n <- src row ((n>>2)&3)*1024 + (n>>4)*4 + (n&3)
__global__ void k_cvt_perm(const float* __restrict__ src, bf16* __restrict__ dst) {
  const int n = blockIdx.x;                 // 0..4095 (permuted row)
  const int orig = ((n>>2)&3)*1024 + (n>>4)*4 + (n&3);
  const float4 v = ((const float4*)(src + (size_t)orig*512))[threadIdx.x];
  bf16* d = dst + (size_t)n*512 + threadIdx.x*4;
  d[0] = __float2bfloat16(v.x); d[1] = __float2bfloat16(v.y);
  d[2] = __float2bfloat16(v.z); d[3] = __float2bfloat16(v.w);
}

__global__ void k_cvt_pad(const float* __restrict__ s, bf16* __restrict__ d,
                          long n, long nrows_real, int rowlen) {
  long i = (long)blockIdx.x*blockDim.x + threadIdx.x;
  if (i < n) {
    long r = i / rowlen;
    d[i] = (r < nrows_real) ? __float2bfloat16(s[i]) : __float2bfloat16(0.f);
  }
}

__global__ void k_init(const float* __restrict__ hx, bf16* __restrict__ hinit,
                       unsigned* __restrict__ flags) {
  int i = blockIdx.x*blockDim.x + threadIdx.x;
  if (i < 8192) flags[i] = 0u;
  if (i < 65536) hinit[i] = __float2bfloat16(hx[i]);
}

__global__ void k_embed(const int* __restrict__ ids, const float* __restrict__ emb_w,
                        bf16* __restrict__ out) {
  const int row = blockIdx.x;
  const int tok = ids[row];
  const float4 v = ((const float4*)(emb_w + (size_t)tok*512))[threadIdx.x];
  bf16* d = out + (size_t)row*512 + threadIdx.x*4;
  d[0] = __float2bfloat16(v.x); d[1] = __float2bfloat16(v.y);
  d[2] = __float2bfloat16(v.z); d[3] = __float2bfloat16(v.w);
}

// ---------------------------------------------------------------------------
extern "C" void kernel_launch(void* const* d_in, const int* in_sizes, int n_in,
                              void* d_out, int out_size, void* d_ws, size_t ws_size,
                              hipStream_t stream) {
  const int*   ids  = (const int*)d_in[0];
  const float* hx   = (const float*)d_in[1];
  const float* cx   = (const float*)d_in[2];
  const float* embw = (const float*)d_in[3];
  const float* Wih0 = (const float*)d_in[4];
  const float* Whh0 = (const float*)d_in[5];
  const float* bih0 = (const float*)d_in[6];
  const float* bhh0 = (const float*)d_in[7];
  const float* Wih1 = (const float*)d_in[8];
  const float* Whh1 = (const float*)d_in[9];
  const float* bih1 = (const float*)d_in[10];
  const float* bhh1 = (const float*)d_in[11];
  const float* Wp   = (const float*)d_in[12];
  const float* bp   = (const float*)d_in[13];
  const float* Wd   = (const float*)d_in[14];
  const float* bd   = (const float*)d_in[15];
  float* out = (float*)d_out;

  char* w = (char*)d_ws;
  bf16* Wih0b = (bf16*)w; w += 4096l*512*2;       // permuted rows
  bf16* Wpack = (bf16*)w; w += 256l*96*64*8*2;    // 24 MB packed recurrent weights
  bf16* Wpb   = (bf16*)w; w += 512l*1024*2;
  bf16* Wdb   = (bf16*)w; w += 50048l*512*2;
  bf16* embb  = (bf16*)w; w += 2048l*512*2;
  float* g0p  = (float*)w; w += 2048l*4096*4;     // [b][t][r][q] layout
  bf16* h0a   = (bf16*)w; w += 2048l*1024*2;
  bf16* h1a   = (bf16*)w; w += 2048l*1024*2;
  bf16* hinit = (bf16*)w; w += 2l*32*1024*2;
  bf16* pb    = (bf16*)w; w += 2048l*512*2;
  unsigned* flags = (unsigned*)w; w += 8192*4;

  k_cvt_perm<<<4096, 128, 0, stream>>>(Wih0, Wih0b);
  k_cvt<<<(512l*1024 + 255)/256, 256, 0, stream>>>(Wp, Wpb, 512l*1024);
  k_cvt_pad<<<(50048l*512 + 255)/256, 256, 0, stream>>>(Wd, Wdb, 50048l*512, 50000, 512);
  k_init<<<256, 256, 0, stream>>>(hx, hinit, flags);
  k_embed<<<2048, 128, 0, stream>>>(ids, embw, embb);
  k_pack<<<256, 256, 0, stream>>>(Whh0, Wih1, Whh1, Wpack);

  // layer-0 input-side GEMM for ALL timesteps -> g0p layout; folds bih0+bhh0
  gemm_bt<2><<<dim3(32, 16), 256, 0, stream>>>(
      embb, Wih0b, bih0, bhh0, g0p, nullptr, 2048, 4096, 512, 4096);

  // persistent pipelined recurrence: one dispatch, 65 super-steps
  float* tail = out + 102400000l;
  k_lstm_persist<<<256, 256, 0, stream>>>(hinit, cx, Wpack, g0p, bih1, bhh1,
                                          h0a, h1a, tail, flags);

  // predictor: Linear + BN(eval) + tanh -> bf16
  gemm_bt<1><<<dim3(4, 16), 256, 0, stream>>>(
      h1a, Wpb, bp, nullptr, nullptr, pb, 2048, 512, 1024, 512);

  // decoder: [2048,512] @ [50048,512]^T (padded), 1D swizzled grid,
  // round-9 scalar epilogue, guarded store to 50000
  gemm_bt<0><<<391*16, 256, 0, stream>>>(
      pb, Wdb, bd, nullptr, out, nullptr, 2048, 50048, 512, 50000);
}

// Round 14
// 734.609 us; speedup vs baseline: 1.0707x; 1.0525x over previous
//
#include <hip/hip_runtime.h>
#include <hip/hip_bf16.h>

using bf16 = __hip_bfloat16;
typedef __attribute__((ext_vector_type(8))) short short8;   // 8 bf16 = 4 VGPRs
typedef __attribute__((ext_vector_type(4))) float f32x4;    // MFMA C/D frag

#define MFMA_BF16(A,B,C) __builtin_amdgcn_mfma_f32_16x16x32_bf16((A),(B),(C),0,0,0)

static __device__ __forceinline__ unsigned bf16bits(float f) {
  union { bf16 h; unsigned short u; } cv; cv.h = __float2bfloat16(f); return cv.u;
}

// async global->LDS, 16B per lane. LDS dest = wave-uniform base + lane*16.
static __device__ __forceinline__ void gload16(const void* g, void* l) {
  __builtin_amdgcn_global_load_lds(
      (const __attribute__((address_space(1))) void*)g,
      (__attribute__((address_space(3))) void*)l, 16, 0, 0);
}

// ---------------------------------------------------------------------------
// Generic bf16 GEMM: C[M,N] = A[M,K] @ B[N,K]^T (+bias)
// m97 structure: 128x128 tile, BK=32, 4 waves (2x2), 4x4 16x16x32 frags/wave.
// 2D grid, x = N-panel (fastest): concurrent blocks write adjacent column
// stripes of the same rows -> best C-write page locality (the 410MB fp32
// decoder write dominates; XCD panel-swizzle measured -35us, rejected).
// EPI 0: fp32 out.  EPI 1: tanh(x*BN_SCALE) -> bf16.  EPI 2: g0p scatter.
// ---------------------------------------------------------------------------
template<int EPI>
__global__ __launch_bounds__(256)
void gemm_bt(const bf16* __restrict__ A, const bf16* __restrict__ B,
             const float* __restrict__ bias1, const float* __restrict__ bias2,
             float* __restrict__ Cf, bf16* __restrict__ Cb,
             int M, int N, int K, int Nreal)
{
  __shared__ __align__(1024) bf16 As[128*32];
  __shared__ __align__(1024) bf16 Bs[128*32];
  const int tid  = threadIdx.x;
  const int wave = tid >> 6, lane = tid & 63;
  const int wr = wave >> 1, wc = wave & 1;
  const int row0 = blockIdx.y * 128;
  const int col0 = blockIdx.x * 128;

  f32x4 acc[4][4];
  #pragma unroll
  for (int m = 0; m < 4; ++m)
    #pragma unroll
    for (int n = 0; n < 4; ++n) { f32x4 z = {0.f,0.f,0.f,0.f}; acc[m][n] = z; }

  const int r_sub = lane >> 2;   // 0..15 (row within 16-row stage group)
  const int kc    = lane & 3;    // 16B chunk within 64B row

  for (int k0 = 0; k0 < K; k0 += 32) {
    __syncthreads();
    #pragma unroll
    for (int j = 0; j < 2; ++j) {
      const int rb = wave*32 + j*16;
      gload16(A + (size_t)(row0 + rb + r_sub)*K + k0 + kc*8,
              (void*)((char*)As + (size_t)rb*64));
      gload16(B + (size_t)(col0 + rb + r_sub)*K + k0 + kc*8,
              (void*)((char*)Bs + (size_t)rb*64));
    }
    __syncthreads();

    short8 af[4], bfv[4];
    #pragma unroll
    for (int m = 0; m < 4; ++m)
      af[m] = *(const short8*)(As + (wr*64 + m*16 + (lane&15))*32 + (lane>>4)*8);
    #pragma unroll
    for (int n = 0; n < 4; ++n)
      bfv[n] = *(const short8*)(Bs + (wc*64 + n*16 + (lane&15))*32 + (lane>>4)*8);
    #pragma unroll
    for (int m = 0; m < 4; ++m)
      #pragma unroll
      for (int n = 0; n < 4; ++n)
        acc[m][n] = MFMA_BF16(af[m], bfv[n], acc[m][n]);
  }

  const float BN_SCALE = 0.9999950000374997f;  // 1/sqrt(1+1e-5)
  #pragma unroll
  for (int m = 0; m < 4; ++m) {
    const int rg0 = row0 + wr*64 + m*16 + ((lane>>4)<<2);
    #pragma unroll
    for (int n = 0; n < 4; ++n) {
      const int cg = col0 + wc*64 + n*16 + (lane&15);
      if (EPI == 2) {
        const int bq = cg >> 4, q = cg & 15;
        const int orig = (q>>2)*1024 + bq*4 + (q&3);   // permuted -> original col
        const float bb = bias1[orig] + bias2[orig];
        #pragma unroll
        for (int j = 0; j < 4; ++j) {
          const int row = rg0 + j;
          Cf[((size_t)bq*64 + (row>>5))*512 + (size_t)(row&31)*16 + q]
              = acc[m][n][j] + bb;
        }
      } else if (cg < Nreal) {
        float bb = 0.f;
        if (bias1) bb += bias1[cg];
        if (bias2) bb += bias2[cg];
        #pragma unroll
        for (int j = 0; j < 4; ++j) {
          float v = acc[m][n][j] + bb;
          if (EPI == 1) {
            v = tanhf(v * BN_SCALE);
            Cb[(size_t)(rg0+j)*Nreal + cg] = __float2bfloat16(v);
          } else {
            Cf[(size_t)(rg0+j)*Nreal + cg] = v;
          }
        }
      }
    }
  }
}

// ---------------------------------------------------------------------------
// Persistent LSTM recurrence — round-9 proven structure, ONE change: the
// wave-0 poll loop spins hot (no s_sleep) to cut flag-detection latency.
// Safe: wave 0 is the only runnable wave on its CU during the poll (waves
// 1-3 are parked at s_barrier); producers run on other CUs.
// Weights: LDS (96KB, staged once). h reads: normal cached loads (per-XCD L2
// as broadcast cache). h publish: 8B agent-relaxed stores (LLC).
// Flag publish/poll: inline-asm sc0 sc1 relaxed ops (no buffer_wbl2; asm
// volatile prevents the compiler reordering that hung round 8).
// ---------------------------------------------------------------------------
__global__ __launch_bounds__(256, 1)
void k_lstm_persist(const bf16* __restrict__ hinit, const float* __restrict__ cx,
                    const bf16* __restrict__ Wpack, const float* __restrict__ g0p,
                    const float* __restrict__ bih1, const float* __restrict__ bhh1,
                    bf16* __restrict__ h0_all, bf16* __restrict__ h1_all,
                    float* __restrict__ tail, unsigned* __restrict__ flags)
{
  const int b    = blockIdx.x;
  const int tid  = threadIdx.x;
  const int wave = tid >> 6, lane = tid & 63;

  __shared__ __align__(1024) bf16 Wlds[96*512];   // 96 KB: [chunk][lane][8]
  __shared__ float P[4][2][32][20];               // partial sums (padded)

  // one-time: stage this block's packed weights into LDS
  const bf16* wbase = Wpack + (size_t)b * 96 * 512;
  #pragma unroll
  for (int it = 0; it < 24; ++it) {
    const int chunk = it*4 + wave;                // wave-uniform
    gload16(wbase + (size_t)chunk*512 + lane*8,
            (void*)((char*)Wlds + (size_t)chunk*1024));
  }

  // gate/cell phase mapping: one LSTM cell per thread
  const int layer = tid >> 7;
  const int cell  = tid & 127;
  const int r     = cell >> 2;
  const int hc    = cell & 3;
  const int col   = b*4 + hc;
  float creg = cx[(size_t)layer*32768 + (size_t)r*1024 + col];
  float bsum[4];
  #pragma unroll
  for (int g = 0; g < 4; ++g)
    bsum[g] = (layer == 1) ? (bih1[g*1024 + col] + bhh1[g*1024 + col]) : 0.f;

  const int arow = lane & 15;
  const int koff = (lane >> 4) * 8;

  // per-lane poll pointers (wave 0 only uses them)
  const unsigned* fp0 = flags + (lane*4+0)*32;
  const unsigned* fp1 = flags + (lane*4+1)*32;
  const unsigned* fp2 = flags + (lane*4+2)*32;
  const unsigned* fp3 = flags + (lane*4+3)*32;

  __syncthreads();   // weights staged (drains vmcnt incl. global_load_lds)

  for (int s = 0; s < 65; ++s) {
    const bf16* hA = (s == 0) ? hinit           : h0_all + (size_t)(s-1)*32768;
    const bf16* hB = (s <= 1) ? (hinit + 32768) : h1_all + (size_t)(s-2)*32768;

    // normal cached h loads (L2 broadcast); all issued up front
    short8 a0[8], a1[8], c0[8], c1[8];
    #pragma unroll
    for (int i = 0; i < 8; ++i) {
      const int kb = wave*256 + i*32 + koff;
      a0[i] = *(const short8*)(hA + (size_t)arow*1024      + kb);
      a1[i] = *(const short8*)(hA + (size_t)(arow+16)*1024 + kb);
      c0[i] = *(const short8*)(hB + (size_t)arow*1024      + kb);
      c1[i] = *(const short8*)(hB + (size_t)(arow+16)*1024 + kb);
    }
    float gpre[4] = {0.f, 0.f, 0.f, 0.f};
    if (layer == 0 && s < 64) {
      const float* gr = g0p + ((size_t)(b*64 + s)*32 + r)*16;
      #pragma unroll
      for (int g = 0; g < 4; ++g) gpre[g] = gr[g*4 + hc];
    }

    f32x4 z = {0.f,0.f,0.f,0.f};
    f32x4 acc00 = z, acc01 = z, acc10 = z, acc11 = z;
    #pragma unroll
    for (int i = 0; i < 8; ++i) {
      const int ks = wave*8 + i;
      short8 w0 = *(const short8*)(Wlds + ((size_t)(     ks)*64 + lane)*8);
      short8 w1 = *(const short8*)(Wlds + ((size_t)(32 + ks)*64 + lane)*8);
      short8 w2 = *(const short8*)(Wlds + ((size_t)(64 + ks)*64 + lane)*8);
      acc00 = MFMA_BF16(a0[i], w0, acc00);   // layer0: Whh0 @ h0[s-1]
      acc01 = MFMA_BF16(a1[i], w0, acc01);
      acc10 = MFMA_BF16(a0[i], w1, acc10);   // layer1: Wih1 @ h0[s-1]
      acc11 = MFMA_BF16(a1[i], w1, acc11);
      acc10 = MFMA_BF16(c0[i], w2, acc10);   // layer1 += Whh1 @ h1[s-2]
      acc11 = MFMA_BF16(c1[i], w2, acc11);
    }

    #pragma unroll
    for (int j = 0; j < 4; ++j) {
      const int pr = (lane >> 4)*4 + j;
      P[wave][0][pr     ][lane & 15] = acc00[j];
      P[wave][0][pr + 16][lane & 15] = acc01[j];
      P[wave][1][pr     ][lane & 15] = acc10[j];
      P[wave][1][pr + 16][lane & 15] = acc11[j];
    }
    __syncthreads();                         // #1: P complete

    const int t = s - layer;
    if (t >= 0 && t < 64) {
      float v[4];
      #pragma unroll
      for (int g = 0; g < 4; ++g) {
        const int j = g*4 + hc;
        v[g] = P[0][layer][r][j] + P[1][layer][r][j]
             + P[2][layer][r][j] + P[3][layer][r][j] + bsum[g] + gpre[g];
      }
      const float iv = 1.f/(1.f + expf(-v[0]));
      const float fv = 1.f/(1.f + expf(-v[1]));
      const float gv = tanhf(v[2]);
      const float ov = 1.f/(1.f + expf(-v[3]));
      creg = fv*creg + iv*gv;
      const float hn = ov*tanhf(creg);
      // gather 4 cells -> one 8B agent-relaxed store straight to LLC
      unsigned hu  = bf16bits(hn);
      unsigned p01 = hu | ((unsigned)__shfl_xor((int)hu, 1) << 16);
      unsigned p23 = (unsigned)__shfl_xor((int)p01, 2);
      if (hc == 0) {
        bf16* hp = (layer ? h1_all : h0_all) + (size_t)t*32768 + (size_t)r*1024 + b*4;
        unsigned long long v64 = (unsigned long long)p01
                               | ((unsigned long long)p23 << 32);
        __hip_atomic_store((unsigned long long*)hp, v64,
                           __ATOMIC_RELAXED, __HIP_MEMORY_SCOPE_AGENT);
      }
      if (t == 63) {
        tail[(size_t)layer*32768 + (size_t)r*1024 + col]         = hn;
        tail[65536 + (size_t)layer*32768 + (size_t)r*1024 + col] = creg;
      }
    }
    if (s == 64) break;

    __syncthreads();                         // #2: drain h publishes (vmcnt 0)
    if (tid == 0) {
      // RELAXED publish straight to LLC (sc1), pinned by asm volatile:
      // no buffer_wbl2, no compiler reordering.
      asm volatile("global_store_dword %0, %1, off sc0 sc1\n\t"
                   "s_waitcnt vmcnt(0)"
                   :: "v"(flags + b*32), "v"((unsigned)(s + 1)) : "memory");
    }
    if (wave == 0) {                         // only wave 0 polls (hot spin)
      const unsigned su = (unsigned)s;
      for (;;) {
        unsigned v0, v1, v2, v3;
        asm volatile("global_load_dword %0, %1, off sc0 sc1" : "=v"(v0) : "v"(fp0));
        asm volatile("global_load_dword %0, %1, off sc0 sc1" : "=v"(v1) : "v"(fp1));
        asm volatile("global_load_dword %0, %1, off sc0 sc1" : "=v"(v2) : "v"(fp2));
        asm volatile("global_load_dword %0, %1, off sc0 sc1" : "=v"(v3) : "v"(fp3));
        asm volatile("s_waitcnt vmcnt(0)" ::: "memory");
        bool ok = (v0 > su) & (v1 > su) & (v2 > su) & (v3 > su);
        if (__all(ok)) break;
      }
    }
    __syncthreads();                         // #3: release all waves
    asm volatile("" ::: "memory");           // no hoisting of h loads above
    __builtin_amdgcn_sched_barrier(0);
  }
}

// ---------------------------------------------------------------------------
// Pack Whh0 / Wih1 / Whh1 into per-block MFMA-fragment order (bf16).
// ---------------------------------------------------------------------------
__global__ __launch_bounds__(256)
void k_pack(const float* __restrict__ Whh0, const float* __restrict__ Wih1,
            const float* __restrict__ Whh1, bf16* __restrict__ Wpack)
{
  const int b = blockIdx.x;
  #pragma unroll 4
  for (int it = 0; it < 24; ++it) {
    const int idx = it*256 + threadIdx.x;
    const int chunkp = idx >> 6;            // 0..95
    const int l = idx & 63;
    const int p = chunkp >> 5, c = chunkp & 31;
    const float* W = (p == 0) ? Whh0 : (p == 1 ? Wih1 : Whh1);
    const int j = l & 15;
    const int row = (j>>2)*1024 + b*4 + (j&3);
    const int k = c*32 + (l>>4)*8;
    const float* src = W + (size_t)row*1024 + k;
    bf16* dst = Wpack + ((size_t)(b*96 + chunkp)*64 + l)*8;
    #pragma unroll
    for (int q = 0; q < 8; ++q) dst[q] = __float2bfloat16(src[q]);
  }
}

// ---------------------------------------------------------------------------
// small helpers
// ---------------------------------------------------------------------------
__global__ void k_cvt(const float* __restrict__ s, bf16* __restrict__ d, long n) {
  long i = (long)blockIdx.x*blockDim.x + threadIdx.x;
  if (i < n) d[i] = __float2bfloat16(s[i]);
}

// Wih0 cast with ROW PERMUTATION: dst row n <- src row ((n>>2)&3)*1024 + (n>>4)*4 + (n&3)
__global__ void k_cvt_perm(const float* __restrict__ src, bf16* __restrict__ dst) {
  const int n = blockIdx.x;                 // 0..4095 (permuted row)
  const int orig = ((n>>2)&3)*1024 + (n>>4)*4 + (n&3);
  const float4 v = ((const float4*)(src + (size_t)orig*512))[threadIdx.x];
  bf16* d = dst + (size_t)n*512 + threadIdx.x*4;
  d[0] = __float2bfloat16(v.x); d[1] = __float2bfloat16(v.y);
  d[2] = __float2bfloat16(v.z); d[3] = __float2bfloat16(v.w);
}

__global__ void k_cvt_pad(const float* __restrict__ s, bf16* __restrict__ d,
                          long n, long nrows_real, int rowlen) {
  long i = (long)blockIdx.x*blockDim.x + threadIdx.x;
  if (i < n) {
    long r = i / rowlen;
    d[i] = (r < nrows_real) ? __float2bfloat16(s[i]) : __float2bfloat16(0.f);
  }
}

__global__ void k_init(const float* __restrict__ hx, bf16* __restrict__ hinit,
                       unsigned* __restrict__ flags) {
  int i = blockIdx.x*blockDim.x + threadIdx.x;
  if (i < 8192) flags[i] = 0u;
  if (i < 65536) hinit[i] = __float2bfloat16(hx[i]);
}

__global__ void k_embed(const int* __restrict__ ids, const float* __restrict__ emb_w,
                        bf16* __restrict__ out) {
  const int row = blockIdx.x;
  const int tok = ids[row];
  const float4 v = ((const float4*)(emb_w + (size_t)tok*512))[threadIdx.x];
  bf16* d = out + (size_t)row*512 + threadIdx.x*4;
  d[0] = __float2bfloat16(v.x); d[1] = __float2bfloat16(v.y);
  d[2] = __float2bfloat16(v.z); d[3] = __float2bfloat16(v.w);
}

// ---------------------------------------------------------------------------
extern "C" void kernel_launch(void* const* d_in, const int* in_sizes, int n_in,
                              void* d_out, int out_size, void* d_ws, size_t ws_size,
                              hipStream_t stream) {
  const int*   ids  = (const int*)d_in[0];
  const float* hx   = (const float*)d_in[1];
  const float* cx   = (const float*)d_in[2];
  const float* embw = (const float*)d_in[3];
  const float* Wih0 = (const float*)d_in[4];
  const float* Whh0 = (const float*)d_in[5];
  const float* bih0 = (const float*)d_in[6];
  const float* bhh0 = (const float*)d_in[7];
  const float* Wih1 = (const float*)d_in[8];
  const float* Whh1 = (const float*)d_in[9];
  const float* bih1 = (const float*)d_in[10];
  const float* bhh1 = (const float*)d_in[11];
  const float* Wp   = (const float*)d_in[12];
  const float* bp   = (const float*)d_in[13];
  const float* Wd   = (const float*)d_in[14];
  const float* bd   = (const float*)d_in[15];
  float* out = (float*)d_out;

  char* w = (char*)d_ws;
  bf16* Wih0b = (bf16*)w; w += 4096l*512*2;       // permuted rows
  bf16* Wpack = (bf16*)w; w += 256l*96*64*8*2;    // 24 MB packed recurrent weights
  bf16* Wpb   = (bf16*)w; w += 512l*1024*2;
  bf16* Wdb   = (bf16*)w; w += 50048l*512*2;
  bf16* embb  = (bf16*)w; w += 2048l*512*2;
  float* g0p  = (float*)w; w += 2048l*4096*4;     // [b][t][r][q] layout
  bf16* h0a   = (bf16*)w; w += 2048l*1024*2;
  bf16* h1a   = (bf16*)w; w += 2048l*1024*2;
  bf16* hinit = (bf16*)w; w += 2l*32*1024*2;
  bf16* pb    = (bf16*)w; w += 2048l*512*2;
  unsigned* flags = (unsigned*)w; w += 8192*4;

  k_cvt_perm<<<4096, 128, 0, stream>>>(Wih0, Wih0b);
  k_cvt<<<(512l*1024 + 255)/256, 256, 0, stream>>>(Wp, Wpb, 512l*1024);
  k_cvt_pad<<<(50048l*512 + 255)/256, 256, 0, stream>>>(Wd, Wdb, 50048l*512, 50000, 512);
  k_init<<<256, 256, 0, stream>>>(hx, hinit, flags);
  k_embed<<<2048, 128, 0, stream>>>(ids, embw, embb);
  k_pack<<<256, 256, 0, stream>>>(Whh0, Wih1, Whh1, Wpack);

  // layer-0 input-side GEMM for ALL timesteps -> g0p layout; folds bih0+bhh0
  gemm_bt<2><<<dim3(32, 16), 256, 0, stream>>>(
      embb, Wih0b, bih0, bhh0, g0p, nullptr, 2048, 4096, 512, 4096);

  // persistent pipelined recurrence: one dispatch, 65 super-steps
  float* tail = out + 102400000l;
  k_lstm_persist<<<256, 256, 0, stream>>>(hinit, cx, Wpack, g0p, bih1, bhh1,
                                          h0a, h1a, tail, flags);

  // predictor: Linear + BN(eval) + tanh -> bf16
  gemm_bt<1><<<dim3(4, 16), 256, 0, stream>>>(
      h1a, Wpb, bp, nullptr, nullptr, pb, 2048, 512, 1024, 512);

  // decoder: [2048,512] @ [50048,512]^T (padded), 2D grid (x = panel,
  // proven write-locality order), guarded store to 50000
  gemm_bt<0><<<dim3(391, 16), 256, 0, stream>>>(
      pb, Wdb, bd, nullptr, out, nullptr, 2048, 50048, 512, 50000);
}

// Round 15
// 731.793 us; speedup vs baseline: 1.0749x; 1.0038x over previous
//
#include <hip/hip_runtime.h>
#include <hip/hip_bf16.h>

using bf16 = __hip_bfloat16;
typedef __attribute__((ext_vector_type(8))) short short8;   // 8 bf16 = 4 VGPRs
typedef __attribute__((ext_vector_type(4))) float f32x4;    // MFMA C/D frag

#define MFMA_BF16(A,B,C) __builtin_amdgcn_mfma_f32_16x16x32_bf16((A),(B),(C),0,0,0)

static __device__ __forceinline__ unsigned bf16bits(float f) {
  union { bf16 h; unsigned short u; } cv; cv.h = __float2bfloat16(f); return cv.u;
}

// async global->LDS, 16B per lane. LDS dest = wave-uniform base + lane*16.
static __device__ __forceinline__ void gload16(const void* g, void* l) {
  __builtin_amdgcn_global_load_lds(
      (const __attribute__((address_space(1))) void*)g,
      (__attribute__((address_space(3))) void*)l, 16, 0, 0);
}

// ---------------------------------------------------------------------------
// Generic bf16 GEMM: C[M,N] = A[M,K] @ B[N,K]^T (+bias)
// m97 structure: 128x128 tile, BK=32, 4 waves (2x2), 4x4 16x16x32 frags/wave.
// EPI 1: tanh(x*BN_SCALE) -> bf16 (predictor).  EPI 2: g0p scatter.
// ---------------------------------------------------------------------------
template<int EPI>
__global__ __launch_bounds__(256)
void gemm_bt(const bf16* __restrict__ A, const bf16* __restrict__ B,
             const float* __restrict__ bias1, const float* __restrict__ bias2,
             float* __restrict__ Cf, bf16* __restrict__ Cb,
             int M, int N, int K, int Nreal)
{
  __shared__ __align__(1024) bf16 As[128*32];
  __shared__ __align__(1024) bf16 Bs[128*32];
  const int tid  = threadIdx.x;
  const int wave = tid >> 6, lane = tid & 63;
  const int wr = wave >> 1, wc = wave & 1;
  const int row0 = blockIdx.y * 128;
  const int col0 = blockIdx.x * 128;

  f32x4 acc[4][4];
  #pragma unroll
  for (int m = 0; m < 4; ++m)
    #pragma unroll
    for (int n = 0; n < 4; ++n) { f32x4 z = {0.f,0.f,0.f,0.f}; acc[m][n] = z; }

  const int r_sub = lane >> 2;   // 0..15 (row within 16-row stage group)
  const int kc    = lane & 3;    // 16B chunk within 64B row

  for (int k0 = 0; k0 < K; k0 += 32) {
    __syncthreads();
    #pragma unroll
    for (int j = 0; j < 2; ++j) {
      const int rb = wave*32 + j*16;
      gload16(A + (size_t)(row0 + rb + r_sub)*K + k0 + kc*8,
              (void*)((char*)As + (size_t)rb*64));
      gload16(B + (size_t)(col0 + rb + r_sub)*K + k0 + kc*8,
              (void*)((char*)Bs + (size_t)rb*64));
    }
    __syncthreads();

    short8 af[4], bfv[4];
    #pragma unroll
    for (int m = 0; m < 4; ++m)
      af[m] = *(const short8*)(As + (wr*64 + m*16 + (lane&15))*32 + (lane>>4)*8);
    #pragma unroll
    for (int n = 0; n < 4; ++n)
      bfv[n] = *(const short8*)(Bs + (wc*64 + n*16 + (lane&15))*32 + (lane>>4)*8);
    #pragma unroll
    for (int m = 0; m < 4; ++m)
      #pragma unroll
      for (int n = 0; n < 4; ++n)
        acc[m][n] = MFMA_BF16(af[m], bfv[n], acc[m][n]);
  }

  const float BN_SCALE = 0.9999950000374997f;  // 1/sqrt(1+1e-5)
  #pragma unroll
  for (int m = 0; m < 4; ++m) {
    const int rg0 = row0 + wr*64 + m*16 + ((lane>>4)<<2);
    #pragma unroll
    for (int n = 0; n < 4; ++n) {
      const int cg = col0 + wc*64 + n*16 + (lane&15);
      if (EPI == 2) {
        const int bq = cg >> 4, q = cg & 15;
        const int orig = (q>>2)*1024 + bq*4 + (q&3);   // permuted -> original col
        const float bb = bias1[orig] + bias2[orig];
        #pragma unroll
        for (int j = 0; j < 4; ++j) {
          const int row = rg0 + j;
          Cf[((size_t)bq*64 + (row>>5))*512 + (size_t)(row&31)*16 + q]
              = acc[m][n][j] + bb;
        }
      } else if (cg < Nreal) {
        float bb = 0.f;
        if (bias1) bb += bias1[cg];
        if (bias2) bb += bias2[cg];
        #pragma unroll
        for (int j = 0; j < 4; ++j) {
          float v = acc[m][n][j] + bb;
          v = tanhf(v * BN_SCALE);
          Cb[(size_t)(rg0+j)*Nreal + cg] = __float2bfloat16(v);
        }
      }
    }
  }
}

// ---------------------------------------------------------------------------
// Decoder GEMM: 256x256 tile, 512 threads (8 waves as 2x4 of 128x64
// wave-tiles), BK=32. Halves total staged fetch vs 128^2 (B refetch 16->8,
// A refetch 391->196: 1.64GB -> 0.82GB) — the decoder is fetch-volume-bound
// (per-block dur ~53us vs 0.5us MFMA at 128^2). Same staging pattern and
// scalar epilogue as the proven gemm_bt. acc 8x4 f32x4 = 128 VGPR.
// ---------------------------------------------------------------------------
__global__ __launch_bounds__(512, 2)
void gemm_dec(const bf16* __restrict__ A, const bf16* __restrict__ B,
              const float* __restrict__ bias, float* __restrict__ C,
              int M, int N, int K, int Nreal)
{
  __shared__ __align__(1024) bf16 As[256*32];
  __shared__ __align__(1024) bf16 Bs[256*32];
  const int tid  = threadIdx.x;
  const int wave = tid >> 6, lane = tid & 63;
  const int wr = wave >> 2, wc = wave & 3;   // 2 x 4 wave grid
  const int row0 = blockIdx.y * 256;
  const int col0 = blockIdx.x * 256;

  f32x4 acc[8][4];
  #pragma unroll
  for (int m = 0; m < 8; ++m)
    #pragma unroll
    for (int n = 0; n < 4; ++n) { f32x4 z = {0.f,0.f,0.f,0.f}; acc[m][n] = z; }

  const int r_sub = lane >> 2;   // row within 16-row stage group
  const int kc    = lane & 3;    // 16B chunk within 64B row

  for (int k0 = 0; k0 < K; k0 += 32) {
    __syncthreads();
    #pragma unroll
    for (int j = 0; j < 2; ++j) {
      const int rb = wave*32 + j*16;           // 8 waves x 32 rows = 256
      gload16(A + (size_t)(row0 + rb + r_sub)*K + k0 + kc*8,
              (void*)((char*)As + (size_t)rb*64));
      gload16(B + (size_t)(col0 + rb + r_sub)*K + k0 + kc*8,
              (void*)((char*)Bs + (size_t)rb*64));
    }
    __syncthreads();

    short8 af[8], bfv[4];
    #pragma unroll
    for (int m = 0; m < 8; ++m)
      af[m] = *(const short8*)(As + (wr*128 + m*16 + (lane&15))*32 + (lane>>4)*8);
    #pragma unroll
    for (int n = 0; n < 4; ++n)
      bfv[n] = *(const short8*)(Bs + (wc*64 + n*16 + (lane&15))*32 + (lane>>4)*8);
    #pragma unroll
    for (int m = 0; m < 8; ++m)
      #pragma unroll
      for (int n = 0; n < 4; ++n)
        acc[m][n] = MFMA_BF16(af[m], bfv[n], acc[m][n]);
  }

  #pragma unroll
  for (int m = 0; m < 8; ++m) {
    const int rg0 = row0 + wr*128 + m*16 + ((lane>>4)<<2);
    #pragma unroll
    for (int n = 0; n < 4; ++n) {
      const int cg = col0 + wc*64 + n*16 + (lane&15);
      if (cg < Nreal) {
        const float bb = bias[cg];
        #pragma unroll
        for (int j = 0; j < 4; ++j)
          C[(size_t)(rg0+j)*Nreal + cg] = acc[m][n][j] + bb;
      }
    }
  }
}

// ---------------------------------------------------------------------------
// Persistent LSTM recurrence — proven structure (rounds 9/11/13/14),
// UNTOUCHED this round. Weights: LDS (96KB, staged once). h reads: normal
// cached loads (per-XCD L2 broadcast). h publish: 8B agent-relaxed stores
// (LLC). Flag publish/poll: inline-asm sc0 sc1 relaxed (no buffer_wbl2).
// ---------------------------------------------------------------------------
__global__ __launch_bounds__(256, 1)
void k_lstm_persist(const bf16* __restrict__ hinit, const float* __restrict__ cx,
                    const bf16* __restrict__ Wpack, const float* __restrict__ g0p,
                    const float* __restrict__ bih1, const float* __restrict__ bhh1,
                    bf16* __restrict__ h0_all, bf16* __restrict__ h1_all,
                    float* __restrict__ tail, unsigned* __restrict__ flags)
{
  const int b    = blockIdx.x;
  const int tid  = threadIdx.x;
  const int wave = tid >> 6, lane = tid & 63;

  __shared__ __align__(1024) bf16 Wlds[96*512];   // 96 KB: [chunk][lane][8]
  __shared__ float P[4][2][32][20];               // partial sums (padded)

  // one-time: stage this block's packed weights into LDS
  const bf16* wbase = Wpack + (size_t)b * 96 * 512;
  #pragma unroll
  for (int it = 0; it < 24; ++it) {
    const int chunk = it*4 + wave;                // wave-uniform
    gload16(wbase + (size_t)chunk*512 + lane*8,
            (void*)((char*)Wlds + (size_t)chunk*1024));
  }

  // gate/cell phase mapping: one LSTM cell per thread
  const int layer = tid >> 7;
  const int cell  = tid & 127;
  const int r     = cell >> 2;
  const int hc    = cell & 3;
  const int col   = b*4 + hc;
  float creg = cx[(size_t)layer*32768 + (size_t)r*1024 + col];
  float bsum[4];
  #pragma unroll
  for (int g = 0; g < 4; ++g)
    bsum[g] = (layer == 1) ? (bih1[g*1024 + col] + bhh1[g*1024 + col]) : 0.f;

  const int arow = lane & 15;
  const int koff = (lane >> 4) * 8;

  // per-lane poll pointers (wave 0 only uses them)
  const unsigned* fp0 = flags + (lane*4+0)*32;
  const unsigned* fp1 = flags + (lane*4+1)*32;
  const unsigned* fp2 = flags + (lane*4+2)*32;
  const unsigned* fp3 = flags + (lane*4+3)*32;

  __syncthreads();   // weights staged (drains vmcnt incl. global_load_lds)

  for (int s = 0; s < 65; ++s) {
    const bf16* hA = (s == 0) ? hinit           : h0_all + (size_t)(s-1)*32768;
    const bf16* hB = (s <= 1) ? (hinit + 32768) : h1_all + (size_t)(s-2)*32768;

    // normal cached h loads (L2 broadcast); all issued up front
    short8 a0[8], a1[8], c0[8], c1[8];
    #pragma unroll
    for (int i = 0; i < 8; ++i) {
      const int kb = wave*256 + i*32 + koff;
      a0[i] = *(const short8*)(hA + (size_t)arow*1024      + kb);
      a1[i] = *(const short8*)(hA + (size_t)(arow+16)*1024 + kb);
      c0[i] = *(const short8*)(hB + (size_t)arow*1024      + kb);
      c1[i] = *(const short8*)(hB + (size_t)(arow+16)*1024 + kb);
    }
    float gpre[4] = {0.f, 0.f, 0.f, 0.f};
    if (layer == 0 && s < 64) {
      const float* gr = g0p + ((size_t)(b*64 + s)*32 + r)*16;
      #pragma unroll
      for (int g = 0; g < 4; ++g) gpre[g] = gr[g*4 + hc];
    }

    f32x4 z = {0.f,0.f,0.f,0.f};
    f32x4 acc00 = z, acc01 = z, acc10 = z, acc11 = z;
    #pragma unroll
    for (int i = 0; i < 8; ++i) {
      const int ks = wave*8 + i;
      short8 w0 = *(const short8*)(Wlds + ((size_t)(     ks)*64 + lane)*8);
      short8 w1 = *(const short8*)(Wlds + ((size_t)(32 + ks)*64 + lane)*8);
      short8 w2 = *(const short8*)(Wlds + ((size_t)(64 + ks)*64 + lane)*8);
      acc00 = MFMA_BF16(a0[i], w0, acc00);   // layer0: Whh0 @ h0[s-1]
      acc01 = MFMA_BF16(a1[i], w0, acc01);
      acc10 = MFMA_BF16(a0[i], w1, acc10);   // layer1: Wih1 @ h0[s-1]
      acc11 = MFMA_BF16(a1[i], w1, acc11);
      acc10 = MFMA_BF16(c0[i], w2, acc10);   // layer1 += Whh1 @ h1[s-2]
      acc11 = MFMA_BF16(c1[i], w2, acc11);
    }

    #pragma unroll
    for (int j = 0; j < 4; ++j) {
      const int pr = (lane >> 4)*4 + j;
      P[wave][0][pr     ][lane & 15] = acc00[j];
      P[wave][0][pr + 16][lane & 15] = acc01[j];
      P[wave][1][pr     ][lane & 15] = acc10[j];
      P[wave][1][pr + 16][lane & 15] = acc11[j];
    }
    __syncthreads();                         // #1: P complete

    const int t = s - layer;
    if (t >= 0 && t < 64) {
      float v[4];
      #pragma unroll
      for (int g = 0; g < 4; ++g) {
        const int j = g*4 + hc;
        v[g] = P[0][layer][r][j] + P[1][layer][r][j]
             + P[2][layer][r][j] + P[3][layer][r][j] + bsum[g] + gpre[g];
      }
      const float iv = 1.f/(1.f + expf(-v[0]));
      const float fv = 1.f/(1.f + expf(-v[1]));
      const float gv = tanhf(v[2]);
      const float ov = 1.f/(1.f + expf(-v[3]));
      creg = fv*creg + iv*gv;
      const float hn = ov*tanhf(creg);
      // gather 4 cells -> one 8B agent-relaxed store straight to LLC
      unsigned hu  = bf16bits(hn);
      unsigned p01 = hu | ((unsigned)__shfl_xor((int)hu, 1) << 16);
      unsigned p23 = (unsigned)__shfl_xor((int)p01, 2);
      if (hc == 0) {
        bf16* hp = (layer ? h1_all : h0_all) + (size_t)t*32768 + (size_t)r*1024 + b*4;
        unsigned long long v64 = (unsigned long long)p01
                               | ((unsigned long long)p23 << 32);
        __hip_atomic_store((unsigned long long*)hp, v64,
                           __ATOMIC_RELAXED, __HIP_MEMORY_SCOPE_AGENT);
      }
      if (t == 63) {
        tail[(size_t)layer*32768 + (size_t)r*1024 + col]         = hn;
        tail[65536 + (size_t)layer*32768 + (size_t)r*1024 + col] = creg;
      }
    }
    if (s == 64) break;

    __syncthreads();                         // #2: drain h publishes (vmcnt 0)
    if (tid == 0) {
      // RELAXED publish straight to LLC (sc1), pinned by asm volatile:
      // no buffer_wbl2, no compiler reordering.
      asm volatile("global_store_dword %0, %1, off sc0 sc1\n\t"
                   "s_waitcnt vmcnt(0)"
                   :: "v"(flags + b*32), "v"((unsigned)(s + 1)) : "memory");
    }
    if (wave == 0) {                         // only wave 0 polls
      const unsigned su = (unsigned)s;
      for (;;) {
        unsigned v0, v1, v2, v3;
        asm volatile("global_load_dword %0, %1, off sc0 sc1" : "=v"(v0) : "v"(fp0));
        asm volatile("global_load_dword %0, %1, off sc0 sc1" : "=v"(v1) : "v"(fp1));
        asm volatile("global_load_dword %0, %1, off sc0 sc1" : "=v"(v2) : "v"(fp2));
        asm volatile("global_load_dword %0, %1, off sc0 sc1" : "=v"(v3) : "v"(fp3));
        asm volatile("s_waitcnt vmcnt(0)" ::: "memory");
        bool ok = (v0 > su) & (v1 > su) & (v2 > su) & (v3 > su);
        if (__all(ok)) break;
        __builtin_amdgcn_s_sleep(1);
      }
    }
    __syncthreads();                         // #3: release all waves
    asm volatile("" ::: "memory");           // no hoisting of h loads above
    __builtin_amdgcn_sched_barrier(0);
  }
}

// ---------------------------------------------------------------------------
// Pack Whh0 / Wih1 / Whh1 into per-block MFMA-fragment order (bf16).
// ---------------------------------------------------------------------------
__global__ __launch_bounds__(256)
void k_pack(const float* __restrict__ Whh0, const float* __restrict__ Wih1,
            const float* __restrict__ Whh1, bf16* __restrict__ Wpack)
{
  const int b = blockIdx.x;
  #pragma unroll 4
  for (int it = 0; it < 24; ++it) {
    const int idx = it*256 + threadIdx.x;
    const int chunkp = idx >> 6;            // 0..95
    const int l = idx & 63;
    const int p = chunkp >> 5, c = chunkp & 31;
    const float* W = (p == 0) ? Whh0 : (p == 1 ? Wih1 : Whh1);
    const int j = l & 15;
    const int row = (j>>2)*1024 + b*4 + (j&3);
    const int k = c*32 + (l>>4)*8;
    const float* src = W + (size_t)row*1024 + k;
    bf16* dst = Wpack + ((size_t)(b*96 + chunkp)*64 + l)*8;
    #pragma unroll
    for (int q = 0; q < 8; ++q) dst[q] = __float2bfloat16(src[q]);
  }
}

// ---------------------------------------------------------------------------
// small helpers
// ---------------------------------------------------------------------------
__global__ void k_cvt(const float* __restrict__ s, bf16* __restrict__ d, long n) {
  long i = (long)blockIdx.x*blockDim.x + threadIdx.x;
  if (i < n) d[i] = __float2bfloat16(s[i]);
}

// Wih0 cast with ROW PERMUTATION: dst row n <- src row ((n>>2)&3)*1024 + (n>>4)*4 + (n&3)
__global__ void k_cvt_perm(const float* __restrict__ src, bf16* __restrict__ dst) {
  const int n = blockIdx.x;                 // 0..4095 (permuted row)
  const int orig = ((n>>2)&3)*1024 + (n>>4)*4 + (n&3);
  const float4 v = ((const float4*)(src + (size_t)orig*512))[threadIdx.x];
  bf16* d = dst + (size_t)n*512 + threadIdx.x*4;
  d[0] = __float2bfloat16(v.x); d[1] = __float2bfloat16(v.y);
  d[2] = __float2bfloat16(v.z); d[3] = __float2bfloat16(v.w);
}

__global__ void k_cvt_pad(const float* __restrict__ s, bf16* __restrict__ d,
                          long n, long nrows_real, int rowlen) {
  long i = (long)blockIdx.x*blockDim.x + threadIdx.x;
  if (i < n) {
    long r = i / rowlen;
    d[i] = (r < nrows_real) ? __float2bfloat16(s[i]) : __float2bfloat16(0.f);
  }
}

__global__ void k_init(const float* __restrict__ hx, bf16* __restrict__ hinit,
                       unsigned* __restrict__ flags) {
  int i = blockIdx.x*blockDim.x + threadIdx.x;
  if (i < 8192) flags[i] = 0u;
  if (i < 65536) hinit[i] = __float2bfloat16(hx[i]);
}

__global__ void k_embed(const int* __restrict__ ids, const float* __restrict__ emb_w,
                        bf16* __restrict__ out) {
  const int row = blockIdx.x;
  const int tok = ids[row];
  const float4 v = ((const float4*)(emb_w + (size_t)tok*512))[threadIdx.x];
  bf16* d = out + (size_t)row*512 + threadIdx.x*4;
  d[0] = __float2bfloat16(v.x); d[1] = __float2bfloat16(v.y);
  d[2] = __float2bfloat16(v.z); d[3] = __float2bfloat16(v.w);
}

// ---------------------------------------------------------------------------
extern "C" void kernel_launch(void* const* d_in, const int* in_sizes, int n_in,
                              void* d_out, int out_size, void* d_ws, size_t ws_size,
                              hipStream_t stream) {
  const int*   ids  = (const int*)d_in[0];
  const float* hx   = (const float*)d_in[1];
  const float* cx   = (const float*)d_in[2];
  const float* embw = (const float*)d_in[3];
  const float* Wih0 = (const float*)d_in[4];
  const float* Whh0 = (const float*)d_in[5];
  const float* bih0 = (const float*)d_in[6];
  const float* bhh0 = (const float*)d_in[7];
  const float* Wih1 = (const float*)d_in[8];
  const float* Whh1 = (const float*)d_in[9];
  const float* bih1 = (const float*)d_in[10];
  const float* bhh1 = (const float*)d_in[11];
  const float* Wp   = (const float*)d_in[12];
  const float* bp   = (const float*)d_in[13];
  const float* Wd   = (const float*)d_in[14];
  const float* bd   = (const float*)d_in[15];
  float* out = (float*)d_out;

  char* w = (char*)d_ws;
  bf16* Wih0b = (bf16*)w; w += 4096l*512*2;       // permuted rows
  bf16* Wpack = (bf16*)w; w += 256l*96*64*8*2;    // 24 MB packed recurrent weights
  bf16* Wpb   = (bf16*)w; w += 512l*1024*2;
  bf16* Wdb   = (bf16*)w; w += 50176l*512*2;      // padded to 196*256 rows
  bf16* embb  = (bf16*)w; w += 2048l*512*2;
  float* g0p  = (float*)w; w += 2048l*4096*4;     // [b][t][r][q] layout
  bf16* h0a   = (bf16*)w; w += 2048l*1024*2;
  bf16* h1a   = (bf16*)w; w += 2048l*1024*2;
  bf16* hinit = (bf16*)w; w += 2l*32*1024*2;
  bf16* pb    = (bf16*)w; w += 2048l*512*2;
  unsigned* flags = (unsigned*)w; w += 8192*4;

  k_cvt_perm<<<4096, 128, 0, stream>>>(Wih0, Wih0b);
  k_cvt<<<(512l*1024 + 255)/256, 256, 0, stream>>>(Wp, Wpb, 512l*1024);
  k_cvt_pad<<<(50176l*512 + 255)/256, 256, 0, stream>>>(Wd, Wdb, 50176l*512, 50000, 512);
  k_init<<<256, 256, 0, stream>>>(hx, hinit, flags);
  k_embed<<<2048, 128, 0, stream>>>(ids, embw, embb);
  k_pack<<<256, 256, 0, stream>>>(Whh0, Wih1, Whh1, Wpack);

  // layer-0 input-side GEMM for ALL timesteps -> g0p layout; folds bih0+bhh0
  gemm_bt<2><<<dim3(32, 16), 256, 0, stream>>>(
      embb, Wih0b, bih0, bhh0, g0p, nullptr, 2048, 4096, 512, 4096);

  // persistent pipelined recurrence: one dispatch, 65 super-steps
  float* tail = out + 102400000l;
  k_lstm_persist<<<256, 256, 0, stream>>>(hinit, cx, Wpack, g0p, bih1, bhh1,
                                          h0a, h1a, tail, flags);

  // predictor: Linear + BN(eval) + tanh -> bf16
  gemm_bt<1><<<dim3(4, 16), 256, 0, stream>>>(
      h1a, Wpb, bp, nullptr, nullptr, pb, 2048, 512, 1024, 512);

  // decoder: [2048,512] @ [50176,512]^T (padded), 256x256 tiles (halved
  // fetch volume), 2D grid x = panel, guarded store to 50000
  gemm_dec<<<dim3(196, 8), 512, 0, stream>>>(
      pb, Wdb, bd, out, 2048, 50176, 512, 50000);
}

// Round 16
// 723.367 us; speedup vs baseline: 1.0874x; 1.0116x over previous
//
#include <hip/hip_runtime.h>
#include <hip/hip_bf16.h>

using bf16 = __hip_bfloat16;
typedef __attribute__((ext_vector_type(8))) short short8;   // 8 bf16 = 4 VGPRs
typedef __attribute__((ext_vector_type(4))) float f32x4;    // MFMA C/D frag

#define MFMA_BF16(A,B,C) __builtin_amdgcn_mfma_f32_16x16x32_bf16((A),(B),(C),0,0,0)

static __device__ __forceinline__ unsigned bf16bits(float f) {
  union { bf16 h; unsigned short u; } cv; cv.h = __float2bfloat16(f); return cv.u;
}

// async global->LDS, 16B per lane. LDS dest = wave-uniform base + lane*16.
static __device__ __forceinline__ void gload16(const void* g, void* l) {
  __builtin_amdgcn_global_load_lds(
      (const __attribute__((address_space(1))) void*)g,
      (__attribute__((address_space(3))) void*)l, 16, 0, 0);
}

// ---------------------------------------------------------------------------
// Generic bf16 GEMM: C[M,N] = A[M,K] @ B[N,K]^T (+bias)
// m97 structure: 128x128 tile, BK=32, 4 waves (2x2), 4x4 16x16x32 frags/wave.
// EPI 1: tanh(x*BN_SCALE) -> bf16 (predictor).  EPI 2: g0p scatter.
// ---------------------------------------------------------------------------
template<int EPI>
__global__ __launch_bounds__(256)
void gemm_bt(const bf16* __restrict__ A, const bf16* __restrict__ B,
             const float* __restrict__ bias1, const float* __restrict__ bias2,
             float* __restrict__ Cf, bf16* __restrict__ Cb,
             int M, int N, int K, int Nreal)
{
  __shared__ __align__(1024) bf16 As[128*32];
  __shared__ __align__(1024) bf16 Bs[128*32];
  const int tid  = threadIdx.x;
  const int wave = tid >> 6, lane = tid & 63;
  const int wr = wave >> 1, wc = wave & 1;
  const int row0 = blockIdx.y * 128;
  const int col0 = blockIdx.x * 128;

  f32x4 acc[4][4];
  #pragma unroll
  for (int m = 0; m < 4; ++m)
    #pragma unroll
    for (int n = 0; n < 4; ++n) { f32x4 z = {0.f,0.f,0.f,0.f}; acc[m][n] = z; }

  const int r_sub = lane >> 2;   // 0..15 (row within 16-row stage group)
  const int kc    = lane & 3;    // 16B chunk within 64B row

  for (int k0 = 0; k0 < K; k0 += 32) {
    __syncthreads();
    #pragma unroll
    for (int j = 0; j < 2; ++j) {
      const int rb = wave*32 + j*16;
      gload16(A + (size_t)(row0 + rb + r_sub)*K + k0 + kc*8,
              (void*)((char*)As + (size_t)rb*64));
      gload16(B + (size_t)(col0 + rb + r_sub)*K + k0 + kc*8,
              (void*)((char*)Bs + (size_t)rb*64));
    }
    __syncthreads();

    short8 af[4], bfv[4];
    #pragma unroll
    for (int m = 0; m < 4; ++m)
      af[m] = *(const short8*)(As + (wr*64 + m*16 + (lane&15))*32 + (lane>>4)*8);
    #pragma unroll
    for (int n = 0; n < 4; ++n)
      bfv[n] = *(const short8*)(Bs + (wc*64 + n*16 + (lane&15))*32 + (lane>>4)*8);
    #pragma unroll
    for (int m = 0; m < 4; ++m)
      #pragma unroll
      for (int n = 0; n < 4; ++n)
        acc[m][n] = MFMA_BF16(af[m], bfv[n], acc[m][n]);
  }

  const float BN_SCALE = 0.9999950000374997f;  // 1/sqrt(1+1e-5)
  #pragma unroll
  for (int m = 0; m < 4; ++m) {
    const int rg0 = row0 + wr*64 + m*16 + ((lane>>4)<<2);
    #pragma unroll
    for (int n = 0; n < 4; ++n) {
      const int cg = col0 + wc*64 + n*16 + (lane&15);
      if (EPI == 2) {
        const int bq = cg >> 4, q = cg & 15;
        const int orig = (q>>2)*1024 + bq*4 + (q&3);   // permuted -> original col
        const float bb = bias1[orig] + bias2[orig];
        #pragma unroll
        for (int j = 0; j < 4; ++j) {
          const int row = rg0 + j;
          Cf[((size_t)bq*64 + (row>>5))*512 + (size_t)(row&31)*16 + q]
              = acc[m][n][j] + bb;
        }
      } else if (cg < Nreal) {
        float bb = 0.f;
        if (bias1) bb += bias1[cg];
        if (bias2) bb += bias2[cg];
        #pragma unroll
        for (int j = 0; j < 4; ++j) {
          float v = acc[m][n][j] + bb;
          v = tanhf(v * BN_SCALE);
          Cb[(size_t)(rg0+j)*Nreal + cg] = __float2bfloat16(v);
        }
      }
    }
  }
}

// ---------------------------------------------------------------------------
// Decoder GEMM v2: 256x256 tile, 512 threads (2x4 waves of 128x64), BK=32,
// DOUBLE-BUFFERED staging with counted vmcnt (T3/T4): stages k and k+1 stay
// in flight across RAW s_barrier (no __syncthreads vmcnt(0) drain). At
// 1 block/CU there is no co-resident block to hide LLC staging latency —
// the 2-barrier drain loop serialized fetch+compute (256^2-tile fetch-volume
// halving was NULL, so the bound is latency, not bandwidth).
// Per iter: vmcnt(4)=stage k landed -> s_barrier -> ds_read+MFMA ->
// lgkmcnt(0)+sched_barrier (#18) -> s_barrier -> stage k+2 into freed buf.
// ---------------------------------------------------------------------------
__global__ __launch_bounds__(512, 2)
void gemm_dec(const bf16* __restrict__ A, const bf16* __restrict__ B,
              const float* __restrict__ bias, float* __restrict__ C,
              int M, int N, int K, int Nreal)
{
  __shared__ __align__(1024) bf16 As[2*256*32];   // 32KB: [slot][row][32]
  __shared__ __align__(1024) bf16 Bs[2*256*32];
  const int tid  = threadIdx.x;
  const int wave = tid >> 6, lane = tid & 63;
  const int wr = wave >> 2, wc = wave & 3;   // 2 x 4 wave grid
  const int row0 = blockIdx.y * 256;
  const int col0 = blockIdx.x * 256;

  f32x4 acc[8][4];
  #pragma unroll
  for (int m = 0; m < 8; ++m)
    #pragma unroll
    for (int n = 0; n < 4; ++n) { f32x4 z = {0.f,0.f,0.f,0.f}; acc[m][n] = z; }

  const int r_sub = lane >> 2;   // row within 16-row stage group
  const int kc    = lane & 3;    // 16B chunk within 64B row

  // stage K-step (k0 bf16 offset) into LDS slot sl: 4 gload16 per wave
  auto STAGE = [&](int sl, int k0) {
    #pragma unroll
    for (int j = 0; j < 2; ++j) {
      const int rb = wave*32 + j*16;           // 8 waves x 32 rows = 256
      gload16(A + (size_t)(row0 + rb + r_sub)*K + k0 + kc*8,
              (void*)((char*)As + (size_t)sl*16384 + (size_t)rb*64));
      gload16(B + (size_t)(col0 + rb + r_sub)*K + k0 + kc*8,
              (void*)((char*)Bs + (size_t)sl*16384 + (size_t)rb*64));
    }
  };

  const int NT = K >> 5;                     // 16 for K=512
  STAGE(0, 0);
  if (NT > 1) STAGE(1, 32);

  for (int kk = 0; kk < NT; ++kk) {
    const int cur = kk & 1;
    // wait for stage kk only (stage kk+1's 4 loads may stay in flight)
    if (kk == NT - 1) asm volatile("s_waitcnt vmcnt(0)" ::: "memory");
    else              asm volatile("s_waitcnt vmcnt(4)" ::: "memory");
    __builtin_amdgcn_sched_barrier(0);
    __builtin_amdgcn_s_barrier();            // all waves' stage-kk landed

    const bf16* Ab = As + (size_t)cur*8192;
    const bf16* Bb = Bs + (size_t)cur*8192;
    short8 af[8], bfv[4];
    #pragma unroll
    for (int m = 0; m < 8; ++m)
      af[m] = *(const short8*)(Ab + (wr*128 + m*16 + (lane&15))*32 + (lane>>4)*8);
    #pragma unroll
    for (int n = 0; n < 4; ++n)
      bfv[n] = *(const short8*)(Bb + (wc*64 + n*16 + (lane&15))*32 + (lane>>4)*8);
    #pragma unroll
    for (int m = 0; m < 8; ++m)
      #pragma unroll
      for (int n = 0; n < 4; ++n)
        acc[m][n] = MFMA_BF16(af[m], bfv[n], acc[m][n]);

    asm volatile("s_waitcnt lgkmcnt(0)" ::: "memory");   // reads of buf done
    __builtin_amdgcn_sched_barrier(0);                   // rule #18
    __builtin_amdgcn_s_barrier();            // all waves done reading buf cur
    if (kk + 2 < NT) STAGE(cur, (kk + 2) * 32);
  }

  #pragma unroll
  for (int m = 0; m < 8; ++m) {
    const int rg0 = row0 + wr*128 + m*16 + ((lane>>4)<<2);
    #pragma unroll
    for (int n = 0; n < 4; ++n) {
      const int cg = col0 + wc*64 + n*16 + (lane&15);
      if (cg < Nreal) {
        const float bb = bias[cg];
        #pragma unroll
        for (int j = 0; j < 4; ++j)
          C[(size_t)(rg0+j)*Nreal + cg] = acc[m][n][j] + bb;
      }
    }
  }
}

// ---------------------------------------------------------------------------
// Persistent LSTM recurrence — proven structure (rounds 9/11/13/14/15),
// UNTOUCHED. Weights: LDS (96KB, staged once). h reads: normal cached loads
// (per-XCD L2 broadcast). h publish: 8B agent-relaxed stores (LLC).
// Flag publish/poll: inline-asm sc0 sc1 relaxed (no buffer_wbl2).
// ---------------------------------------------------------------------------
__global__ __launch_bounds__(256, 1)
void k_lstm_persist(const bf16* __restrict__ hinit, const float* __restrict__ cx,
                    const bf16* __restrict__ Wpack, const float* __restrict__ g0p,
                    const float* __restrict__ bih1, const float* __restrict__ bhh1,
                    bf16* __restrict__ h0_all, bf16* __restrict__ h1_all,
                    float* __restrict__ tail, unsigned* __restrict__ flags)
{
  const int b    = blockIdx.x;
  const int tid  = threadIdx.x;
  const int wave = tid >> 6, lane = tid & 63;

  __shared__ __align__(1024) bf16 Wlds[96*512];   // 96 KB: [chunk][lane][8]
  __shared__ float P[4][2][32][20];               // partial sums (padded)

  // one-time: stage this block's packed weights into LDS
  const bf16* wbase = Wpack + (size_t)b * 96 * 512;
  #pragma unroll
  for (int it = 0; it < 24; ++it) {
    const int chunk = it*4 + wave;                // wave-uniform
    gload16(wbase + (size_t)chunk*512 + lane*8,
            (void*)((char*)Wlds + (size_t)chunk*1024));
  }

  // gate/cell phase mapping: one LSTM cell per thread
  const int layer = tid >> 7;
  const int cell  = tid & 127;
  const int r     = cell >> 2;
  const int hc    = cell & 3;
  const int col   = b*4 + hc;
  float creg = cx[(size_t)layer*32768 + (size_t)r*1024 + col];
  float bsum[4];
  #pragma unroll
  for (int g = 0; g < 4; ++g)
    bsum[g] = (layer == 1) ? (bih1[g*1024 + col] + bhh1[g*1024 + col]) : 0.f;

  const int arow = lane & 15;
  const int koff = (lane >> 4) * 8;

  // per-lane poll pointers (wave 0 only uses them)
  const unsigned* fp0 = flags + (lane*4+0)*32;
  const unsigned* fp1 = flags + (lane*4+1)*32;
  const unsigned* fp2 = flags + (lane*4+2)*32;
  const unsigned* fp3 = flags + (lane*4+3)*32;

  __syncthreads();   // weights staged (drains vmcnt incl. global_load_lds)

  for (int s = 0; s < 65; ++s) {
    const bf16* hA = (s == 0) ? hinit           : h0_all + (size_t)(s-1)*32768;
    const bf16* hB = (s <= 1) ? (hinit + 32768) : h1_all + (size_t)(s-2)*32768;

    // normal cached h loads (L2 broadcast); all issued up front
    short8 a0[8], a1[8], c0[8], c1[8];
    #pragma unroll
    for (int i = 0; i < 8; ++i) {
      const int kb = wave*256 + i*32 + koff;
      a0[i] = *(const short8*)(hA + (size_t)arow*1024      + kb);
      a1[i] = *(const short8*)(hA + (size_t)(arow+16)*1024 + kb);
      c0[i] = *(const short8*)(hB + (size_t)arow*1024      + kb);
      c1[i] = *(const short8*)(hB + (size_t)(arow+16)*1024 + kb);
    }
    float gpre[4] = {0.f, 0.f, 0.f, 0.f};
    if (layer == 0 && s < 64) {
      const float* gr = g0p + ((size_t)(b*64 + s)*32 + r)*16;
      #pragma unroll
      for (int g = 0; g < 4; ++g) gpre[g] = gr[g*4 + hc];
    }

    f32x4 z = {0.f,0.f,0.f,0.f};
    f32x4 acc00 = z, acc01 = z, acc10 = z, acc11 = z;
    #pragma unroll
    for (int i = 0; i < 8; ++i) {
      const int ks = wave*8 + i;
      short8 w0 = *(const short8*)(Wlds + ((size_t)(     ks)*64 + lane)*8);
      short8 w1 = *(const short8*)(Wlds + ((size_t)(32 + ks)*64 + lane)*8);
      short8 w2 = *(const short8*)(Wlds + ((size_t)(64 + ks)*64 + lane)*8);
      acc00 = MFMA_BF16(a0[i], w0, acc00);   // layer0: Whh0 @ h0[s-1]
      acc01 = MFMA_BF16(a1[i], w0, acc01);
      acc10 = MFMA_BF16(a0[i], w1, acc10);   // layer1: Wih1 @ h0[s-1]
      acc11 = MFMA_BF16(a1[i], w1, acc11);
      acc10 = MFMA_BF16(c0[i], w2, acc10);   // layer1 += Whh1 @ h1[s-2]
      acc11 = MFMA_BF16(c1[i], w2, acc11);
    }

    #pragma unroll
    for (int j = 0; j < 4; ++j) {
      const int pr = (lane >> 4)*4 + j;
      P[wave][0][pr     ][lane & 15] = acc00[j];
      P[wave][0][pr + 16][lane & 15] = acc01[j];
      P[wave][1][pr     ][lane & 15] = acc10[j];
      P[wave][1][pr + 16][lane & 15] = acc11[j];
    }
    __syncthreads();                         // #1: P complete

    const int t = s - layer;
    if (t >= 0 && t < 64) {
      float v[4];
      #pragma unroll
      for (int g = 0; g < 4; ++g) {
        const int j = g*4 + hc;
        v[g] = P[0][layer][r][j] + P[1][layer][r][j]
             + P[2][layer][r][j] + P[3][layer][r][j] + bsum[g] + gpre[g];
      }
      const float iv = 1.f/(1.f + expf(-v[0]));
      const float fv = 1.f/(1.f + expf(-v[1]));
      const float gv = tanhf(v[2]);
      const float ov = 1.f/(1.f + expf(-v[3]));
      creg = fv*creg + iv*gv;
      const float hn = ov*tanhf(creg);
      // gather 4 cells -> one 8B agent-relaxed store straight to LLC
      unsigned hu  = bf16bits(hn);
      unsigned p01 = hu | ((unsigned)__shfl_xor((int)hu, 1) << 16);
      unsigned p23 = (unsigned)__shfl_xor((int)p01, 2);
      if (hc == 0) {
        bf16* hp = (layer ? h1_all : h0_all) + (size_t)t*32768 + (size_t)r*1024 + b*4;
        unsigned long long v64 = (unsigned long long)p01
                               | ((unsigned long long)p23 << 32);
        __hip_atomic_store((unsigned long long*)hp, v64,
                           __ATOMIC_RELAXED, __HIP_MEMORY_SCOPE_AGENT);
      }
      if (t == 63) {
        tail[(size_t)layer*32768 + (size_t)r*1024 + col]         = hn;
        tail[65536 + (size_t)layer*32768 + (size_t)r*1024 + col] = creg;
      }
    }
    if (s == 64) break;

    __syncthreads();                         // #2: drain h publishes (vmcnt 0)
    if (tid == 0) {
      // RELAXED publish straight to LLC (sc1), pinned by asm volatile:
      // no buffer_wbl2, no compiler reordering.
      asm volatile("global_store_dword %0, %1, off sc0 sc1\n\t"
                   "s_waitcnt vmcnt(0)"
                   :: "v"(flags + b*32), "v"((unsigned)(s + 1)) : "memory");
    }
    if (wave == 0) {                         // only wave 0 polls
      const unsigned su = (unsigned)s;
      for (;;) {
        unsigned v0, v1, v2, v3;
        asm volatile("global_load_dword %0, %1, off sc0 sc1" : "=v"(v0) : "v"(fp0));
        asm volatile("global_load_dword %0, %1, off sc0 sc1" : "=v"(v1) : "v"(fp1));
        asm volatile("global_load_dword %0, %1, off sc0 sc1" : "=v"(v2) : "v"(fp2));
        asm volatile("global_load_dword %0, %1, off sc0 sc1" : "=v"(v3) : "v"(fp3));
        asm volatile("s_waitcnt vmcnt(0)" ::: "memory");
        bool ok = (v0 > su) & (v1 > su) & (v2 > su) & (v3 > su);
        if (__all(ok)) break;
        __builtin_amdgcn_s_sleep(1);
      }
    }
    __syncthreads();                         // #3: release all waves
    asm volatile("" ::: "memory");           // no hoisting of h loads above
    __builtin_amdgcn_sched_barrier(0);
  }
}

// ---------------------------------------------------------------------------
// Pack Whh0 / Wih1 / Whh1 into per-block MFMA-fragment order (bf16).
// ---------------------------------------------------------------------------
__global__ __launch_bounds__(256)
void k_pack(const float* __restrict__ Whh0, const float* __restrict__ Wih1,
            const float* __restrict__ Whh1, bf16* __restrict__ Wpack)
{
  const int b = blockIdx.x;
  #pragma unroll 4
  for (int it = 0; it < 24; ++it) {
    const int idx = it*256 + threadIdx.x;
    const int chunkp = idx >> 6;            // 0..95
    const int l = idx & 63;
    const int p = chunkp >> 5, c = chunkp & 31;
    const float* W = (p == 0) ? Whh0 : (p == 1 ? Wih1 : Whh1);
    const int j = l & 15;
    const int row = (j>>2)*1024 + b*4 + (j&3);
    const int k = c*32 + (l>>4)*8;
    const float* src = W + (size_t)row*1024 + k;
    bf16* dst = Wpack + ((size_t)(b*96 + chunkp)*64 + l)*8;
    #pragma unroll
    for (int q = 0; q < 8; ++q) dst[q] = __float2bfloat16(src[q]);
  }
}

// ---------------------------------------------------------------------------
// small helpers
// ---------------------------------------------------------------------------
__global__ void k_cvt(const float* __restrict__ s, bf16* __restrict__ d, long n) {
  long i = (long)blockIdx.x*blockDim.x + threadIdx.x;
  if (i < n) d[i] = __float2bfloat16(s[i]);
}

// Wih0 cast with ROW PERMUTATION: dst row n <- src row ((n>>2)&3)*1024 + (n>>4)*4 + (n&3)
__global__ void k_cvt_perm(const float* __restrict__ src, bf16* __restrict__ dst) {
  const int n = blockIdx.x;                 // 0..4095 (permuted row)
  const int orig = ((n>>2)&3)*1024 + (n>>4)*4 + (n&3);
  const float4 v = ((const float4*)(src + (size_t)orig*512))[threadIdx.x];
  bf16* d = dst + (size_t)n*512 + threadIdx.x*4;
  d[0] = __float2bfloat16(v.x); d[1] = __float2bfloat16(v.y);
  d[2] = __float2bfloat16(v.z); d[3] = __float2bfloat16(v.w);
}

__global__ void k_cvt_pad(const float* __restrict__ s, bf16* __restrict__ d,
                          long n, long nrows_real, int rowlen) {
  long i = (long)blockIdx.x*blockDim.x + threadIdx.x;
  if (i < n) {
    long r = i / rowlen;
    d[i] = (r < nrows_real) ? __float2bfloat16(s[i]) : __float2bfloat16(0.f);
  }
}

__global__ void k_init(const float* __restrict__ hx, bf16* __restrict__ hinit,
                       unsigned* __restrict__ flags) {
  int i = blockIdx.x*blockDim.x + threadIdx.x;
  if (i < 8192) flags[i] = 0u;
  if (i < 65536) hinit[i] = __float2bfloat16(hx[i]);
}

__global__ void k_embed(const int* __restrict__ ids, const float* __restrict__ emb_w,
                        bf16* __restrict__ out) {
  const int row = blockIdx.x;
  const int tok = ids[row];
  const float4 v = ((const float4*)(emb_w + (size_t)tok*512))[threadIdx.x];
  bf16* d = out + (size_t)row*512 + threadIdx.x*4;
  d[0] = __float2bfloat16(v.x); d[1] = __float2bfloat16(v.y);
  d[2] = __float2bfloat16(v.z); d[3] = __float2bfloat16(v.w);
}

// ---------------------------------------------------------------------------
extern "C" void kernel_launch(void* const* d_in, const int* in_sizes, int n_in,
                              void* d_out, int out_size, void* d_ws, size_t ws_size,
                              hipStream_t stream) {
  const int*   ids  = (const int*)d_in[0];
  const float* hx   = (const float*)d_in[1];
  const float* cx   = (const float*)d_in[2];
  const float* embw = (const float*)d_in[3];
  const float* Wih0 = (const float*)d_in[4];
  const float* Whh0 = (const float*)d_in[5];
  const float* bih0 = (const float*)d_in[6];
  const float* bhh0 = (const float*)d_in[7];
  const float* Wih1 = (const float*)d_in[8];
  const float* Whh1 = (const float*)d_in[9];
  const float* bih1 = (const float*)d_in[10];
  const float* bhh1 = (const float*)d_in[11];
  const float* Wp   = (const float*)d_in[12];
  const float* bp   = (const float*)d_in[13];
  const float* Wd   = (const float*)d_in[14];
  const float* bd   = (const float*)d_in[15];
  float* out = (float*)d_out;

  char* w = (char*)d_ws;
  bf16* Wih0b = (bf16*)w; w += 4096l*512*2;       // permuted rows
  bf16* Wpack = (bf16*)w; w += 256l*96*64*8*2;    // 24 MB packed recurrent weights
  bf16* Wpb   = (bf16*)w; w += 512l*1024*2;
  bf16* Wdb   = (bf16*)w; w += 50176l*512*2;      // padded to 196*256 rows
  bf16* embb  = (bf16*)w; w += 2048l*512*2;
  float* g0p  = (float*)w; w += 2048l*4096*4;     // [b][t][r][q] layout
  bf16* h0a   = (bf16*)w; w += 2048l*1024*2;
  bf16* h1a   = (bf16*)w; w += 2048l*1024*2;
  bf16* hinit = (bf16*)w; w += 2l*32*1024*2;
  bf16* pb    = (bf16*)w; w += 2048l*512*2;
  unsigned* flags = (unsigned*)w; w += 8192*4;

  k_cvt_perm<<<4096, 128, 0, stream>>>(Wih0, Wih0b);
  k_cvt<<<(512l*1024 + 255)/256, 256, 0, stream>>>(Wp, Wpb, 512l*1024);
  k_cvt_pad<<<(50176l*512 + 255)/256, 256, 0, stream>>>(Wd, Wdb, 50176l*512, 50000, 512);
  k_init<<<256, 256, 0, stream>>>(hx, hinit, flags);
  k_embed<<<2048, 128, 0, stream>>>(ids, embw, embb);
  k_pack<<<256, 256, 0, stream>>>(Whh0, Wih1, Whh1, Wpack);

  // layer-0 input-side GEMM for ALL timesteps -> g0p layout; folds bih0+bhh0
  gemm_bt<2><<<dim3(32, 16), 256, 0, stream>>>(
      embb, Wih0b, bih0, bhh0, g0p, nullptr, 2048, 4096, 512, 4096);

  // persistent pipelined recurrence: one dispatch, 65 super-steps
  float* tail = out + 102400000l;
  k_lstm_persist<<<256, 256, 0, stream>>>(hinit, cx, Wpack, g0p, bih1, bhh1,
                                          h0a, h1a, tail, flags);

  // predictor: Linear + BN(eval) + tanh -> bf16
  gemm_bt<1><<<dim3(4, 16), 256, 0, stream>>>(
      h1a, Wpb, bp, nullptr, nullptr, pb, 2048, 512, 1024, 512);

  // decoder: [2048,512] @ [50176,512]^T (padded), 256x256 tiles, double-
  // buffered staging w/ counted vmcnt, guarded store to 50000
  gemm_dec<<<dim3(196, 8), 512, 0, stream>>>(
      pb, Wdb, bd, out, 2048, 50176, 512, 50000);
}

// Round 17
// 713.165 us; speedup vs baseline: 1.1029x; 1.0143x over previous
//
#include <hip/hip_runtime.h>
#include <hip/hip_bf16.h>

using bf16 = __hip_bfloat16;
typedef __attribute__((ext_vector_type(8))) short short8;   // 8 bf16 = 4 VGPRs
typedef __attribute__((ext_vector_type(4))) float f32x4;    // MFMA C/D frag

#define MFMA_BF16(A,B,C) __builtin_amdgcn_mfma_f32_16x16x32_bf16((A),(B),(C),0,0,0)

static __device__ __forceinline__ unsigned bf16bits(float f) {
  union { bf16 h; unsigned short u; } cv; cv.h = __float2bfloat16(f); return cv.u;
}

// async global->LDS, 16B per lane. LDS dest = wave-uniform base + lane*16.
static __device__ __forceinline__ void gload16(const void* g, void* l) {
  __builtin_amdgcn_global_load_lds(
      (const __attribute__((address_space(1))) void*)g,
      (__attribute__((address_space(3))) void*)l, 16, 0, 0);
}

// ---------------------------------------------------------------------------
// Generic bf16 GEMM: C[M,N] = A[M,K] @ B[N,K]^T (+bias)
// m97 structure: 128x128 tile, BK=32, 4 waves (2x2), 4x4 16x16x32 frags/wave.
// EPI 1: tanh(x*BN_SCALE) -> bf16 (predictor).  EPI 2: g0p scatter.
// ---------------------------------------------------------------------------
template<int EPI>
__global__ __launch_bounds__(256)
void gemm_bt(const bf16* __restrict__ A, const bf16* __restrict__ B,
             const float* __restrict__ bias1, const float* __restrict__ bias2,
             float* __restrict__ Cf, bf16* __restrict__ Cb,
             int M, int N, int K, int Nreal)
{
  __shared__ __align__(1024) bf16 As[128*32];
  __shared__ __align__(1024) bf16 Bs[128*32];
  const int tid  = threadIdx.x;
  const int wave = tid >> 6, lane = tid & 63;
  const int wr = wave >> 1, wc = wave & 1;
  const int row0 = blockIdx.y * 128;
  const int col0 = blockIdx.x * 128;

  f32x4 acc[4][4];
  #pragma unroll
  for (int m = 0; m < 4; ++m)
    #pragma unroll
    for (int n = 0; n < 4; ++n) { f32x4 z = {0.f,0.f,0.f,0.f}; acc[m][n] = z; }

  const int r_sub = lane >> 2;   // 0..15 (row within 16-row stage group)
  const int kc    = lane & 3;    // 16B chunk within 64B row

  for (int k0 = 0; k0 < K; k0 += 32) {
    __syncthreads();
    #pragma unroll
    for (int j = 0; j < 2; ++j) {
      const int rb = wave*32 + j*16;
      gload16(A + (size_t)(row0 + rb + r_sub)*K + k0 + kc*8,
              (void*)((char*)As + (size_t)rb*64));
      gload16(B + (size_t)(col0 + rb + r_sub)*K + k0 + kc*8,
              (void*)((char*)Bs + (size_t)rb*64));
    }
    __syncthreads();

    short8 af[4], bfv[4];
    #pragma unroll
    for (int m = 0; m < 4; ++m)
      af[m] = *(const short8*)(As + (wr*64 + m*16 + (lane&15))*32 + (lane>>4)*8);
    #pragma unroll
    for (int n = 0; n < 4; ++n)
      bfv[n] = *(const short8*)(Bs + (wc*64 + n*16 + (lane&15))*32 + (lane>>4)*8);
    #pragma unroll
    for (int m = 0; m < 4; ++m)
      #pragma unroll
      for (int n = 0; n < 4; ++n)
        acc[m][n] = MFMA_BF16(af[m], bfv[n], acc[m][n]);
  }

  const float BN_SCALE = 0.9999950000374997f;  // 1/sqrt(1+1e-5)
  #pragma unroll
  for (int m = 0; m < 4; ++m) {
    const int rg0 = row0 + wr*64 + m*16 + ((lane>>4)<<2);
    #pragma unroll
    for (int n = 0; n < 4; ++n) {
      const int cg = col0 + wc*64 + n*16 + (lane&15);
      if (EPI == 2) {
        const int bq = cg >> 4, q = cg & 15;
        const int orig = (q>>2)*1024 + bq*4 + (q&3);   // permuted -> original col
        const float bb = bias1[orig] + bias2[orig];
        #pragma unroll
        for (int j = 0; j < 4; ++j) {
          const int row = rg0 + j;
          Cf[((size_t)bq*64 + (row>>5))*512 + (size_t)(row&31)*16 + q]
              = acc[m][n][j] + bb;
        }
      } else if (cg < Nreal) {
        float bb = 0.f;
        if (bias1) bb += bias1[cg];
        if (bias2) bb += bias2[cg];
        #pragma unroll
        for (int j = 0; j < 4; ++j) {
          float v = acc[m][n][j] + bb;
          v = tanhf(v * BN_SCALE);
          Cb[(size_t)(rg0+j)*Nreal + cg] = __float2bfloat16(v);
        }
      }
    }
  }
}

// ---------------------------------------------------------------------------
// Decoder GEMM v3: 256x256 tile, 512 threads, double-buffered counted-vmcnt
// staging (round 16), plus NON-TEMPORAL C stores: the 410MB fp32 C stream
// was thrashing the per-XCD L2 (evicting the B-panels reused 8x and A reused
// 196x). nt stores keep operand panels L2-resident.
// ---------------------------------------------------------------------------
__global__ __launch_bounds__(512, 2)
void gemm_dec(const bf16* __restrict__ A, const bf16* __restrict__ B,
              const float* __restrict__ bias, float* __restrict__ C,
              int M, int N, int K, int Nreal)
{
  __shared__ __align__(1024) bf16 As[2*256*32];   // 32KB: [slot][row][32]
  __shared__ __align__(1024) bf16 Bs[2*256*32];
  const int tid  = threadIdx.x;
  const int wave = tid >> 6, lane = tid & 63;
  const int wr = wave >> 2, wc = wave & 3;   // 2 x 4 wave grid
  const int row0 = blockIdx.y * 256;
  const int col0 = blockIdx.x * 256;

  f32x4 acc[8][4];
  #pragma unroll
  for (int m = 0; m < 8; ++m)
    #pragma unroll
    for (int n = 0; n < 4; ++n) { f32x4 z = {0.f,0.f,0.f,0.f}; acc[m][n] = z; }

  const int r_sub = lane >> 2;   // row within 16-row stage group
  const int kc    = lane & 3;    // 16B chunk within 64B row

  auto STAGE = [&](int sl, int k0) {
    #pragma unroll
    for (int j = 0; j < 2; ++j) {
      const int rb = wave*32 + j*16;           // 8 waves x 32 rows = 256
      gload16(A + (size_t)(row0 + rb + r_sub)*K + k0 + kc*8,
              (void*)((char*)As + (size_t)sl*16384 + (size_t)rb*64));
      gload16(B + (size_t)(col0 + rb + r_sub)*K + k0 + kc*8,
              (void*)((char*)Bs + (size_t)sl*16384 + (size_t)rb*64));
    }
  };

  const int NT = K >> 5;                     // 16 for K=512
  STAGE(0, 0);
  if (NT > 1) STAGE(1, 32);

  for (int kk = 0; kk < NT; ++kk) {
    const int cur = kk & 1;
    if (kk == NT - 1) asm volatile("s_waitcnt vmcnt(0)" ::: "memory");
    else              asm volatile("s_waitcnt vmcnt(4)" ::: "memory");
    __builtin_amdgcn_sched_barrier(0);
    __builtin_amdgcn_s_barrier();            // all waves' stage-kk landed

    const bf16* Ab = As + (size_t)cur*8192;
    const bf16* Bb = Bs + (size_t)cur*8192;
    short8 af[8], bfv[4];
    #pragma unroll
    for (int m = 0; m < 8; ++m)
      af[m] = *(const short8*)(Ab + (wr*128 + m*16 + (lane&15))*32 + (lane>>4)*8);
    #pragma unroll
    for (int n = 0; n < 4; ++n)
      bfv[n] = *(const short8*)(Bb + (wc*64 + n*16 + (lane&15))*32 + (lane>>4)*8);
    #pragma unroll
    for (int m = 0; m < 8; ++m)
      #pragma unroll
      for (int n = 0; n < 4; ++n)
        acc[m][n] = MFMA_BF16(af[m], bfv[n], acc[m][n]);

    asm volatile("s_waitcnt lgkmcnt(0)" ::: "memory");   // reads of buf done
    __builtin_amdgcn_sched_barrier(0);                   // rule #18
    __builtin_amdgcn_s_barrier();            // all waves done reading buf cur
    if (kk + 2 < NT) STAGE(cur, (kk + 2) * 32);
  }

  #pragma unroll
  for (int m = 0; m < 8; ++m) {
    const int rg0 = row0 + wr*128 + m*16 + ((lane>>4)<<2);
    #pragma unroll
    for (int n = 0; n < 4; ++n) {
      const int cg = col0 + wc*64 + n*16 + (lane&15);
      if (cg < Nreal) {
        const float bb = bias[cg];
        #pragma unroll
        for (int j = 0; j < 4; ++j)
          __builtin_nontemporal_store(acc[m][n][j] + bb,
                                      C + (size_t)(rg0+j)*Nreal + cg);
      }
    }
  }
}

// ---------------------------------------------------------------------------
// Persistent LSTM recurrence — proven structure (rounds 9/11/13/14/15/16),
// UNTOUCHED. Weights: LDS (96KB, staged once). h reads: normal cached loads
// (per-XCD L2 broadcast). h publish: 8B agent-relaxed stores (LLC).
// Flag publish/poll: inline-asm sc0 sc1 relaxed (no buffer_wbl2).
// ---------------------------------------------------------------------------
__global__ __launch_bounds__(256, 1)
void k_lstm_persist(const bf16* __restrict__ hinit, const float* __restrict__ cx,
                    const bf16* __restrict__ Wpack, const float* __restrict__ g0p,
                    const float* __restrict__ bih1, const float* __restrict__ bhh1,
                    bf16* __restrict__ h0_all, bf16* __restrict__ h1_all,
                    float* __restrict__ tail, unsigned* __restrict__ flags)
{
  const int b    = blockIdx.x;
  const int tid  = threadIdx.x;
  const int wave = tid >> 6, lane = tid & 63;

  __shared__ __align__(1024) bf16 Wlds[96*512];   // 96 KB: [chunk][lane][8]
  __shared__ float P[4][2][32][20];               // partial sums (padded)

  // one-time: stage this block's packed weights into LDS
  const bf16* wbase = Wpack + (size_t)b * 96 * 512;
  #pragma unroll
  for (int it = 0; it < 24; ++it) {
    const int chunk = it*4 + wave;                // wave-uniform
    gload16(wbase + (size_t)chunk*512 + lane*8,
            (void*)((char*)Wlds + (size_t)chunk*1024));
  }

  // gate/cell phase mapping: one LSTM cell per thread
  const int layer = tid >> 7;
  const int cell  = tid & 127;
  const int r     = cell >> 2;
  const int hc    = cell & 3;
  const int col   = b*4 + hc;
  float creg = cx[(size_t)layer*32768 + (size_t)r*1024 + col];
  float bsum[4];
  #pragma unroll
  for (int g = 0; g < 4; ++g)
    bsum[g] = (layer == 1) ? (bih1[g*1024 + col] + bhh1[g*1024 + col]) : 0.f;

  const int arow = lane & 15;
  const int koff = (lane >> 4) * 8;

  // per-lane poll pointers (wave 0 only uses them)
  const unsigned* fp0 = flags + (lane*4+0)*32;
  const unsigned* fp1 = flags + (lane*4+1)*32;
  const unsigned* fp2 = flags + (lane*4+2)*32;
  const unsigned* fp3 = flags + (lane*4+3)*32;

  __syncthreads();   // weights staged (drains vmcnt incl. global_load_lds)

  for (int s = 0; s < 65; ++s) {
    const bf16* hA = (s == 0) ? hinit           : h0_all + (size_t)(s-1)*32768;
    const bf16* hB = (s <= 1) ? (hinit + 32768) : h1_all + (size_t)(s-2)*32768;

    // normal cached h loads (L2 broadcast); all issued up front
    short8 a0[8], a1[8], c0[8], c1[8];
    #pragma unroll
    for (int i = 0; i < 8; ++i) {
      const int kb = wave*256 + i*32 + koff;
      a0[i] = *(const short8*)(hA + (size_t)arow*1024      + kb);
      a1[i] = *(const short8*)(hA + (size_t)(arow+16)*1024 + kb);
      c0[i] = *(const short8*)(hB + (size_t)arow*1024      + kb);
      c1[i] = *(const short8*)(hB + (size_t)(arow+16)*1024 + kb);
    }
    float gpre[4] = {0.f, 0.f, 0.f, 0.f};
    if (layer == 0 && s < 64) {
      const float* gr = g0p + ((size_t)(b*64 + s)*32 + r)*16;
      #pragma unroll
      for (int g = 0; g < 4; ++g) gpre[g] = gr[g*4 + hc];
    }

    f32x4 z = {0.f,0.f,0.f,0.f};
    f32x4 acc00 = z, acc01 = z, acc10 = z, acc11 = z;
    #pragma unroll
    for (int i = 0; i < 8; ++i) {
      const int ks = wave*8 + i;
      short8 w0 = *(const short8*)(Wlds + ((size_t)(     ks)*64 + lane)*8);
      short8 w1 = *(const short8*)(Wlds + ((size_t)(32 + ks)*64 + lane)*8);
      short8 w2 = *(const short8*)(Wlds + ((size_t)(64 + ks)*64 + lane)*8);
      acc00 = MFMA_BF16(a0[i], w0, acc00);   // layer0: Whh0 @ h0[s-1]
      acc01 = MFMA_BF16(a1[i], w0, acc01);
      acc10 = MFMA_BF16(a0[i], w1, acc10);   // layer1: Wih1 @ h0[s-1]
      acc11 = MFMA_BF16(a1[i], w1, acc11);
      acc10 = MFMA_BF16(c0[i], w2, acc10);   // layer1 += Whh1 @ h1[s-2]
      acc11 = MFMA_BF16(c1[i], w2, acc11);
    }

    #pragma unroll
    for (int j = 0; j < 4; ++j) {
      const int pr = (lane >> 4)*4 + j;
      P[wave][0][pr     ][lane & 15] = acc00[j];
      P[wave][0][pr + 16][lane & 15] = acc01[j];
      P[wave][1][pr     ][lane & 15] = acc10[j];
      P[wave][1][pr + 16][lane & 15] = acc11[j];
    }
    __syncthreads();                         // #1: P complete

    const int t = s - layer;
    if (t >= 0 && t < 64) {
      float v[4];
      #pragma unroll
      for (int g = 0; g < 4; ++g) {
        const int j = g*4 + hc;
        v[g] = P[0][layer][r][j] + P[1][layer][r][j]
             + P[2][layer][r][j] + P[3][layer][r][j] + bsum[g] + gpre[g];
      }
      const float iv = 1.f/(1.f + expf(-v[0]));
      const float fv = 1.f/(1.f + expf(-v[1]));
      const float gv = tanhf(v[2]);
      const float ov = 1.f/(1.f + expf(-v[3]));
      creg = fv*creg + iv*gv;
      const float hn = ov*tanhf(creg);
      // gather 4 cells -> one 8B agent-relaxed store straight to LLC
      unsigned hu  = bf16bits(hn);
      unsigned p01 = hu | ((unsigned)__shfl_xor((int)hu, 1) << 16);
      unsigned p23 = (unsigned)__shfl_xor((int)p01, 2);
      if (hc == 0) {
        bf16* hp = (layer ? h1_all : h0_all) + (size_t)t*32768 + (size_t)r*1024 + b*4;
        unsigned long long v64 = (unsigned long long)p01
                               | ((unsigned long long)p23 << 32);
        __hip_atomic_store((unsigned long long*)hp, v64,
                           __ATOMIC_RELAXED, __HIP_MEMORY_SCOPE_AGENT);
      }
      if (t == 63) {
        tail[(size_t)layer*32768 + (size_t)r*1024 + col]         = hn;
        tail[65536 + (size_t)layer*32768 + (size_t)r*1024 + col] = creg;
      }
    }
    if (s == 64) break;

    __syncthreads();                         // #2: drain h publishes (vmcnt 0)
    if (tid == 0) {
      // RELAXED publish straight to LLC (sc1), pinned by asm volatile:
      // no buffer_wbl2, no compiler reordering.
      asm volatile("global_store_dword %0, %1, off sc0 sc1\n\t"
                   "s_waitcnt vmcnt(0)"
                   :: "v"(flags + b*32), "v"((unsigned)(s + 1)) : "memory");
    }
    if (wave == 0) {                         // only wave 0 polls
      const unsigned su = (unsigned)s;
      for (;;) {
        unsigned v0, v1, v2, v3;
        asm volatile("global_load_dword %0, %1, off sc0 sc1" : "=v"(v0) : "v"(fp0));
        asm volatile("global_load_dword %0, %1, off sc0 sc1" : "=v"(v1) : "v"(fp1));
        asm volatile("global_load_dword %0, %1, off sc0 sc1" : "=v"(v2) : "v"(fp2));
        asm volatile("global_load_dword %0, %1, off sc0 sc1" : "=v"(v3) : "v"(fp3));
        asm volatile("s_waitcnt vmcnt(0)" ::: "memory");
        bool ok = (v0 > su) & (v1 > su) & (v2 > su) & (v3 > su);
        if (__all(ok)) break;
        __builtin_amdgcn_s_sleep(1);
      }
    }
    __syncthreads();                         // #3: release all waves
    asm volatile("" ::: "memory");           // no hoisting of h loads above
    __builtin_amdgcn_sched_barrier(0);
  }
}

// ---------------------------------------------------------------------------
// Pack Whh0 / Wih1 / Whh1 into per-block MFMA-fragment order (bf16).
// ---------------------------------------------------------------------------
__global__ __launch_bounds__(256)
void k_pack(const float* __restrict__ Whh0, const float* __restrict__ Wih1,
            const float* __restrict__ Whh1, bf16* __restrict__ Wpack)
{
  const int b = blockIdx.x;
  #pragma unroll 4
  for (int it = 0; it < 24; ++it) {
    const int idx = it*256 + threadIdx.x;
    const int chunkp = idx >> 6;            // 0..95
    const int l = idx & 63;
    const int p = chunkp >> 5, c = chunkp & 31;
    const float* W = (p == 0) ? Whh0 : (p == 1 ? Wih1 : Whh1);
    const int j = l & 15;
    const int row = (j>>2)*1024 + b*4 + (j&3);
    const int k = c*32 + (l>>4)*8;
    const float* src = W + (size_t)row*1024 + k;
    bf16* dst = Wpack + ((size_t)(b*96 + chunkp)*64 + l)*8;
    #pragma unroll
    for (int q = 0; q < 8; ++q) dst[q] = __float2bfloat16(src[q]);
  }
}

// ---------------------------------------------------------------------------
// small helpers
// ---------------------------------------------------------------------------
__global__ void k_cvt(const float* __restrict__ s, bf16* __restrict__ d, long n) {
  long i = (long)blockIdx.x*blockDim.x + threadIdx.x;
  if (i < n) d[i] = __float2bfloat16(s[i]);
}

// Wih0 cast with ROW PERMUTATION: dst row n <- src row ((n>>2)&3)*1024 + (n>>4)*4 + (n&3)
__global__ void k_cvt_perm(const float* __restrict__ src, bf16* __restrict__ dst) {
  const int n = blockIdx.x;                 // 0..4095 (permuted row)
  const int orig = ((n>>2)&3)*1024 + (n>>4)*4 + (n&3);
  const float4 v = ((const float4*)(src + (size_t)orig*512))[threadIdx.x];
  bf16* d = dst + (size_t)n*512 + threadIdx.x*4;
  d[0] = __float2bfloat16(v.x); d[1] = __float2bfloat16(v.y);
  d[2] = __float2bfloat16(v.z); d[3] = __float2bfloat16(v.w);
}

__global__ void k_cvt_pad(const float* __restrict__ s, bf16* __restrict__ d,
                          long n, long nrows_real, int rowlen) {
  long i = (long)blockIdx.x*blockDim.x + threadIdx.x;
  if (i < n) {
    long r = i / rowlen;
    d[i] = (r < nrows_real) ? __float2bfloat16(s[i]) : __float2bfloat16(0.f);
  }
}

__global__ void k_init(const float* __restrict__ hx, bf16* __restrict__ hinit,
                       unsigned* __restrict__ flags) {
  int i = blockIdx.x*blockDim.x + threadIdx.x;
  if (i < 8192) flags[i] = 0u;
  if (i < 65536) hinit[i] = __float2bfloat16(hx[i]);
}

__global__ void k_embed(const int* __restrict__ ids, const float* __restrict__ emb_w,
                        bf16* __restrict__ out) {
  const int row = blockIdx.x;
  const int tok = ids[row];
  const float4 v = ((const float4*)(emb_w + (size_t)tok*512))[threadIdx.x];
  bf16* d = out + (size_t)row*512 + threadIdx.x*4;
  d[0] = __float2bfloat16(v.x); d[1] = __float2bfloat16(v.y);
  d[2] = __float2bfloat16(v.z); d[3] = __float2bfloat16(v.w);
}

// ---------------------------------------------------------------------------
extern "C" void kernel_launch(void* const* d_in, const int* in_sizes, int n_in,
                              void* d_out, int out_size, void* d_ws, size_t ws_size,
                              hipStream_t stream) {
  const int*   ids  = (const int*)d_in[0];
  const float* hx   = (const float*)d_in[1];
  const float* cx   = (const float*)d_in[2];
  const float* embw = (const float*)d_in[3];
  const float* Wih0 = (const float*)d_in[4];
  const float* Whh0 = (const float*)d_in[5];
  const float* bih0 = (const float*)d_in[6];
  const float* bhh0 = (const float*)d_in[7];
  const float* Wih1 = (const float*)d_in[8];
  const float* Whh1 = (const float*)d_in[9];
  const float* bih1 = (const float*)d_in[10];
  const float* bhh1 = (const float*)d_in[11];
  const float* Wp   = (const float*)d_in[12];
  const float* bp   = (const float*)d_in[13];
  const float* Wd   = (const float*)d_in[14];
  const float* bd   = (const float*)d_in[15];
  float* out = (float*)d_out;

  char* w = (char*)d_ws;
  bf16* Wih0b = (bf16*)w; w += 4096l*512*2;       // permuted rows
  bf16* Wpack = (bf16*)w; w += 256l*96*64*8*2;    // 24 MB packed recurrent weights
  bf16* Wpb   = (bf16*)w; w += 512l*1024*2;
  bf16* Wdb   = (bf16*)w; w += 50176l*512*2;      // padded to 196*256 rows
  bf16* embb  = (bf16*)w; w += 2048l*512*2;
  float* g0p  = (float*)w; w += 2048l*4096*4;     // [b][t][r][q] layout
  bf16* h0a   = (bf16*)w; w += 2048l*1024*2;
  bf16* h1a   = (bf16*)w; w += 2048l*1024*2;
  bf16* hinit = (bf16*)w; w += 2l*32*1024*2;
  bf16* pb    = (bf16*)w; w += 2048l*512*2;
  unsigned* flags = (unsigned*)w; w += 8192*4;

  k_cvt_perm<<<4096, 128, 0, stream>>>(Wih0, Wih0b);
  k_cvt<<<(512l*1024 + 255)/256, 256, 0, stream>>>(Wp, Wpb, 512l*1024);
  k_cvt_pad<<<(50176l*512 + 255)/256, 256, 0, stream>>>(Wd, Wdb, 50176l*512, 50000, 512);
  k_init<<<256, 256, 0, stream>>>(hx, hinit, flags);
  k_embed<<<2048, 128, 0, stream>>>(ids, embw, embb);
  k_pack<<<256, 256, 0, stream>>>(Whh0, Wih1, Whh1, Wpack);

  // layer-0 input-side GEMM for ALL timesteps -> g0p layout; folds bih0+bhh0
  gemm_bt<2><<<dim3(32, 16), 256, 0, stream>>>(
      embb, Wih0b, bih0, bhh0, g0p, nullptr, 2048, 4096, 512, 4096);

  // persistent pipelined recurrence: one dispatch, 65 super-steps
  float* tail = out + 102400000l;
  k_lstm_persist<<<256, 256, 0, stream>>>(hinit, cx, Wpack, g0p, bih1, bhh1,
                                          h0a, h1a, tail, flags);

  // predictor: Linear + BN(eval) + tanh -> bf16
  gemm_bt<1><<<dim3(4, 16), 256, 0, stream>>>(
      h1a, Wpb, bp, nullptr, nullptr, pb, 2048, 512, 1024, 512);

  // decoder: [2048,512] @ [50176,512]^T (padded), 256x256 tiles, double-
  // buffered counted-vmcnt staging, NON-TEMPORAL C stores (L2-pollution fix)
  gemm_dec<<<dim3(196, 8), 512, 0, stream>>>(
      pb, Wdb, bd, out, 2048, 50176, 512, 50000);
}